// Round 2
// baseline (1376.693 us; speedup 1.0000x reference)
//
#include <hip/hip_runtime.h>

#define LRELU_ALPHA 0.2f

// =============================== Phase A: CSR build ===============================

__global__ __launch_bounds__(256) void k_count(const int* __restrict__ dst,
                                               const float* __restrict__ w,
                                               int* __restrict__ cnt,
                                               float* __restrict__ degw, int E) {
  int e = blockIdx.x * 256 + threadIdx.x;
  if (e < E) {
    int d = dst[e];
    atomicAdd(&cnt[d], 1);
    atomicAdd(&degw[d], w[e]);
  }
}

// 3-phase exclusive scan: block-local scan -> scan of block sums -> add offsets
__global__ __launch_bounds__(1024) void k_scan1(const int* __restrict__ cnt,
                                                int* __restrict__ lscan,
                                                int* __restrict__ bsum, int N) {
  __shared__ int sm[1024];
  int t = threadIdx.x;
  int base = blockIdx.x * 1024;
  int v = (base + t < N) ? cnt[base + t] : 0;
  sm[t] = v;
  __syncthreads();
  for (int off = 1; off < 1024; off <<= 1) {
    int x = (t >= off) ? sm[t - off] : 0;
    __syncthreads();
    sm[t] += x;
    __syncthreads();
  }
  if (base + t < N) lscan[base + t] = sm[t] - v;
  if (t == 1023) bsum[blockIdx.x] = sm[1023];
}

__global__ __launch_bounds__(64) void k_scan2(int* __restrict__ bsum,
                                              int* __restrict__ rowptrN, int nb) {
  if (threadIdx.x == 0) {
    int run = 0;
    for (int i = 0; i < nb; ++i) {
      int v = bsum[i];
      bsum[i] = run;
      run += v;
    }
    *rowptrN = run;
  }
}

__global__ __launch_bounds__(1024) void k_scan3(int* __restrict__ rowptr,
                                                int* __restrict__ cur,
                                                const int* __restrict__ bsum, int N) {
  int i = blockIdx.x * 1024 + threadIdx.x;
  if (i < N) {
    int v = rowptr[i] + bsum[blockIdx.x];
    rowptr[i] = v;
    cur[i] = v;
  }
}

__global__ __launch_bounds__(256) void k_scatter(const int* __restrict__ src,
                                                 const int* __restrict__ dst,
                                                 const float* __restrict__ w,
                                                 int* __restrict__ cur,
                                                 int* __restrict__ srcp,
                                                 float* __restrict__ wp, int E) {
  int e = blockIdx.x * 256 + threadIdx.x;
  if (e < E) {
    int d = dst[e];
    int p = atomicAdd(&cur[d], 1);
    srcp[p] = src[e];
    wp[p] = w[e];
  }
}

// =============================== weight packing ===============================
// Wbig [128][272]: cols 0..127  = W0 concat over heads (h*16+f)
//                  cols 128..255= gcn_W0
//                  cols 256..263= va0_src[k][h] = sum_f W0[h,k,f]*a0_src[h,f]
//                  cols 264..271= va0_dst
// va1  [128][16]:  cols 0..7 = W1[h]@a1_src[h], cols 8..15 = W1[h]@a1_dst[h]
// Wstack [1024][128]: row h*128+k = W1[h,k,:] * 0.125  (mean over 8 heads folded in)
__global__ __launch_bounds__(256) void k_pack(const float* __restrict__ W0,
                                              const float* __restrict__ a0s,
                                              const float* __restrict__ a0d,
                                              const float* __restrict__ W1,
                                              const float* __restrict__ a1s,
                                              const float* __restrict__ a1d,
                                              const float* __restrict__ gw0,
                                              float* __restrict__ Wbig,
                                              float* __restrict__ va1,
                                              float* __restrict__ Wstack) {
  int idx = blockIdx.x * 256 + threadIdx.x;
  if (idx < 128 * 272) {
    int k = idx / 272, c = idx % 272;
    float v;
    if (c < 128) {
      int h = c >> 4, f = c & 15;
      v = W0[h * 2048 + k * 16 + f];
    } else if (c < 256) {
      v = gw0[k * 128 + (c - 128)];
    } else if (c < 264) {
      int h = c - 256;
      float s = 0.f;
      for (int f = 0; f < 16; ++f) s += W0[h * 2048 + k * 16 + f] * a0s[h * 16 + f];
      v = s;
    } else {
      int h = c - 264;
      float s = 0.f;
      for (int f = 0; f < 16; ++f) s += W0[h * 2048 + k * 16 + f] * a0d[h * 16 + f];
      v = s;
    }
    Wbig[idx] = v;
  } else if (idx < 128 * 272 + 128 * 16) {
    int j = idx - 34816;
    int k = j >> 4, c = j & 15;
    int h = c & 7;
    const float* a = (c < 8) ? a1s : a1d;
    float s = 0.f;
    for (int f = 0; f < 128; ++f) s += W1[h * 16384 + k * 128 + f] * a[h * 128 + f];
    va1[j] = s;
  } else if (idx < 34816 + 2048 + 131072) {
    int j = idx - 36864;
    int kk = j >> 7, f = j & 127;
    int h = kk >> 7, k = kk & 127;
    Wstack[j] = W1[h * 16384 + k * 128 + f] * 0.125f;
  }
}

// =============================== generic fp32 GEMM ===============================
// C[M,Ncols] = A[M,K] @ B[K,Ncols];  EPI==1: C = max(acc, aux) (final output fuse)
template <int EPI>
__global__ __launch_bounds__(256) void k_gemm(const float* __restrict__ A, int lda,
                                              const float* __restrict__ B, int ldb,
                                              float* __restrict__ C, int ldc,
                                              const float* __restrict__ aux,
                                              int M, int Ncols, int K) {
  __shared__ float As[8][68];  // padded: conflict-free writes, float4-aligned rows
  __shared__ float Bs[8][64];
  int tid = threadIdx.x;
  int tx = tid & 15, ty = tid >> 4;
  int row0 = blockIdx.x * 64, col0 = blockIdx.y * 64;
  float acc[4][4] = {};
  for (int k0 = 0; k0 < K; k0 += 8) {
    __syncthreads();
#pragma unroll
    for (int it = 0; it < 2; ++it) {
      int idx = tid + it * 256;
      int m = idx >> 3, ka = idx & 7;
      int r = row0 + m;
      As[ka][m] = (r < M) ? A[(size_t)r * lda + (k0 + ka)] : 0.f;
      int n = idx & 63, kb = idx >> 6;
      int c = col0 + n;
      Bs[kb][n] = (c < Ncols) ? B[(size_t)(k0 + kb) * ldb + c] : 0.f;
    }
    __syncthreads();
#pragma unroll
    for (int k = 0; k < 8; ++k) {
      float4 a4 = *(const float4*)&As[k][ty * 4];
      float4 b4 = *(const float4*)&Bs[k][tx * 4];
      float av[4] = {a4.x, a4.y, a4.z, a4.w};
      float bv[4] = {b4.x, b4.y, b4.z, b4.w};
#pragma unroll
      for (int i = 0; i < 4; ++i)
#pragma unroll
        for (int j = 0; j < 4; ++j) acc[i][j] += av[i] * bv[j];
    }
  }
#pragma unroll
  for (int i = 0; i < 4; ++i) {
    int r = row0 + ty * 4 + i;
    if (r >= M) continue;
#pragma unroll
    for (int j = 0; j < 4; ++j) {
      int c = col0 + tx * 4 + j;
      if (c >= Ncols) continue;
      float v = acc[i][j];
      if (EPI == 1) v = fmaxf(v, aux[(size_t)r * ldc + c]);
      C[(size_t)r * ldc + c] = v;
    }
  }
}

// =============================== Phase C: layer-0 aggregation ===============================
// one wave per dst node; lane covers dims {2*lane, 2*lane+1}; head = lane>>3
__global__ __launch_bounds__(256) void k_agg0(const float* __restrict__ bufB,
                                              const int* __restrict__ rowptr,
                                              const int* __restrict__ srcp,
                                              const float* __restrict__ wp,
                                              const float* __restrict__ degw,
                                              float* __restrict__ x1,
                                              float* __restrict__ x2, int N) {
  int wave = threadIdx.x >> 6, lane = threadIdx.x & 63;
  int d = blockIdx.x * 4 + wave;
  if (d >= N) return;
  int head = lane >> 3;
  float edv = bufB[(size_t)d * 272 + 264 + head];
  int beg = rowptr[d], end = rowptr[d + 1];
  float l = 0.f, a0 = 0.f, a1 = 0.f, g0 = 0.f, g1 = 0.f;
  for (int i = beg; i < end; ++i) {
    int s = srcp[i];
    float wv = wp[i];
    const float* rs = bufB + (size_t)s * 272;
    float es = rs[256 + head];
    float lg = es + edv;
    lg = lg > 0.f ? lg : LRELU_ALPHA * lg;
    float p = __expf(fminf(lg, 80.f));
    l += p;
    float2 wh = *(const float2*)(rs + 2 * lane);
    float2 hg = *(const float2*)(rs + 128 + 2 * lane);
    a0 += p * wh.x;
    a1 += p * wh.y;
    g0 += wv * hg.x;
    g1 += wv * hg.y;
  }
  float inv = l > 0.f ? 1.f / l : 0.f;
  float v0 = a0 * inv, v1 = a1 * inv;
  v0 = v0 > 0.f ? v0 : __expf(v0) - 1.f;  // ELU
  v1 = v1 > 0.f ? v1 : __expf(v1) - 1.f;
  *(float2*)(x1 + (size_t)d * 128 + 2 * lane) = make_float2(v0, v1);
  float ginv = 1.f / fmaxf(degw[d], 1e-16f);
  float w0 = fmaxf(g0 * ginv, 0.f), w1 = fmaxf(g1 * ginv, 0.f);
  *(float2*)(x2 + (size_t)d * 128 + 2 * lane) = make_float2(w0, w1);
}

// =============================== Phase E: layer-1 aggregation (dst-chunked) ==============
// input-space GAT agg: aggbuf[d-d0, h*128+k] = (1/l_h) * sum_e p_eh * x1[src,k]
// plus GCN layer-1 aggregation -> x2f (relu'd), at global node index
__global__ __launch_bounds__(256) void k_agg1(const float* __restrict__ x1,
                                              const float* __restrict__ h1,
                                              const float* __restrict__ esed,
                                              const int* __restrict__ rowptr,
                                              const int* __restrict__ srcp,
                                              const float* __restrict__ wp,
                                              const float* __restrict__ degw,
                                              float* __restrict__ aggbuf,
                                              float* __restrict__ x2f,
                                              int d0, int d1) {
  int wave = threadIdx.x >> 6, lane = threadIdx.x & 63;
  int d = d0 + blockIdx.x * 4 + wave;
  if (d >= d1) return;
  float ed[8];
#pragma unroll
  for (int h = 0; h < 8; ++h) ed[h] = esed[(size_t)d * 16 + 8 + h];
  int beg = rowptr[d], end = rowptr[d + 1];
  float aggx[8] = {}, aggy[8] = {}, l[8] = {};
  float g0 = 0.f, g1 = 0.f;
  for (int i = beg; i < end; ++i) {
    int s = srcp[i];
    float wv = wp[i];
    float2 xv = *(const float2*)(x1 + (size_t)s * 128 + 2 * lane);
    float2 hv = *(const float2*)(h1 + (size_t)s * 128 + 2 * lane);
    g0 += wv * hv.x;
    g1 += wv * hv.y;
    const float* esrow = esed + (size_t)s * 16;
#pragma unroll
    for (int h = 0; h < 8; ++h) {
      float lg = esrow[h] + ed[h];
      lg = lg > 0.f ? lg : LRELU_ALPHA * lg;
      float p = __expf(fminf(lg, 80.f));
      l[h] += p;
      aggx[h] += p * xv.x;
      aggy[h] += p * xv.y;
    }
  }
  size_t lr = (size_t)(d - d0) * 1024;
#pragma unroll
  for (int h = 0; h < 8; ++h) {
    float inv = l[h] > 0.f ? 1.f / l[h] : 0.f;
    *(float2*)(aggbuf + lr + h * 128 + 2 * lane) =
        make_float2(aggx[h] * inv, aggy[h] * inv);
  }
  float ginv = 1.f / fmaxf(degw[d], 1e-16f);
  float w0 = fmaxf(g0 * ginv, 0.f), w1 = fmaxf(g1 * ginv, 0.f);
  *(float2*)(x2f + (size_t)d * 128 + 2 * lane) = make_float2(w0, w1);
}

// =============================== host launch ===============================

extern "C" void kernel_launch(void* const* d_in, const int* in_sizes, int n_in,
                              void* d_out, int out_size, void* d_ws, size_t ws_size,
                              hipStream_t stream) {
  const float* x   = (const float*)d_in[0];
  const int*   ei  = (const int*)d_in[1];
  const float* ew  = (const float*)d_in[2];
  const float* W0  = (const float*)d_in[3];
  const float* a0s = (const float*)d_in[4];
  const float* a0d = (const float*)d_in[5];
  const float* W1  = (const float*)d_in[6];
  const float* a1s = (const float*)d_in[7];
  const float* a1d = (const float*)d_in[8];
  const float* gw0 = (const float*)d_in[9];
  const float* gw1 = (const float*)d_in[10];
  float* out = (float*)d_out;

  const int N = in_sizes[0] / 128;
  const int E = in_sizes[1] / 2;
  const int* src = ei;
  const int* dst = ei + E;

  // workspace carve (256B aligned slices); peak ~166 MB
  char* p = (char*)d_ws;
  auto carve = [&](size_t bytes) {
    void* r = (void*)p;
    p += (bytes + 255) & ~(size_t)255;
    return r;
  };
  int*   cnt    = (int*)carve((size_t)N * 4);
  float* degw   = (float*)carve((size_t)N * 4);
  int*   rowptr = (int*)carve((size_t)(N + 1) * 4);
  int*   cur    = (int*)carve((size_t)N * 4);
  int*   bsum   = (int*)carve(256 * 4);
  int*   srcp   = (int*)carve((size_t)E * 4);
  float* wp     = (float*)carve((size_t)E * 4);
  float* Wbig   = (float*)carve((size_t)128 * 272 * 4);
  float* va1    = (float*)carve((size_t)128 * 16 * 4);
  float* Wstack = (float*)carve((size_t)1024 * 128 * 4);
  float* bufB   = (float*)carve((size_t)N * 272 * 4);  // reused: esed [N,16] + h1 [N,128]
  float* x1     = (float*)carve((size_t)N * 128 * 4);
  float* x2     = (float*)carve((size_t)N * 128 * 4);  // reused as x2f
  const int CH  = 12800;                               // dst-chunk size (multiple of 64)
  float* aggbuf = (float*)carve((size_t)CH * 1024 * 4);

  float* esed = bufB;
  float* h1   = bufB + (size_t)N * 16;

  // Phase A: CSR build
  hipMemsetAsync(cnt, 0, (size_t)N * 4, stream);
  hipMemsetAsync(degw, 0, (size_t)N * 4, stream);
  int gE = (E + 255) / 256;
  k_count<<<gE, 256, 0, stream>>>(dst, ew, cnt, degw, E);
  int nb = (N + 1023) / 1024;
  k_scan1<<<nb, 1024, 0, stream>>>(cnt, rowptr, bsum, N);
  k_scan2<<<1, 64, 0, stream>>>(bsum, rowptr + N, nb);
  k_scan3<<<nb, 1024, 0, stream>>>(rowptr, cur, bsum, N);
  k_scatter<<<gE, 256, 0, stream>>>(src, dst, ew, cur, srcp, wp, E);

  // weight packing (independent of CSR)
  k_pack<<<(167936 + 255) / 256, 256, 0, stream>>>(W0, a0s, a0d, W1, a1s, a1d, gw0,
                                                   Wbig, va1, Wstack);

  int gM = (N + 63) / 64;
  // Phase B: bufB[N,272] = x @ [W0cat | gcn_W0 | va0_src | va0_dst]
  k_gemm<0><<<dim3(gM, 5), 256, 0, stream>>>(x, 128, Wbig, 272, bufB, 272, nullptr,
                                             N, 272, 128);
  // Phase C: layer-0 GAT softmax-agg + ELU -> x1 ; GCN agg + ReLU -> x2
  k_agg0<<<(N + 3) / 4, 256, 0, stream>>>(bufB, rowptr, srcp, wp, degw, x1, x2, N);

  // Phase D: esed[N,16] = x1 @ va1 ; h1[N,128] = x2 @ gcn_W1
  k_gemm<0><<<dim3(gM, 1), 256, 0, stream>>>(x1, 128, va1, 16, esed, 16, nullptr,
                                             N, 16, 128);
  k_gemm<0><<<dim3(gM, 2), 256, 0, stream>>>(x2, 128, gw1, 128, h1, 128, nullptr,
                                             N, 128, 128);

  // Phase E/F: dst-chunked layer-1 aggregation + output GEMM (aggbuf reused per chunk)
  for (int d0 = 0; d0 < N; d0 += CH) {
    int d1 = d0 + CH < N ? d0 + CH : N;
    int chN = d1 - d0;
    k_agg1<<<(chN + 3) / 4, 256, 0, stream>>>(x1, h1, esed, rowptr, srcp, wp, degw,
                                              aggbuf, x2, d0, d1);
    k_gemm<1><<<dim3((chN + 63) / 64, 2), 256, 0, stream>>>(
        aggbuf, 1024, Wstack, 128, out + (size_t)d0 * 128, 128, x2 + (size_t)d0 * 128,
        chN, 128, 1024);
  }
}

// Round 4
// 646.297 us; speedup vs baseline: 2.1301x; 2.1301x over previous
//
#include <hip/hip_runtime.h>

#define LRELU_ALPHA 0.2f

typedef __attribute__((ext_vector_type(8))) short short8;
typedef __attribute__((ext_vector_type(4))) float float4v;

__device__ __forceinline__ unsigned short f2bf(float f) {
  union { float f; unsigned u; } x; x.f = f;
  unsigned r = (x.u + 0x7fff + ((x.u >> 16) & 1)) >> 16;
  return (unsigned short)r;
}
__device__ __forceinline__ float bf2f(unsigned b) {
  union { unsigned u; float f; } x; x.u = b << 16;
  return x.f;
}

// =============================== Phase A: CSR build ===============================

__global__ __launch_bounds__(256) void k_count(const int* __restrict__ dst,
                                               const float* __restrict__ w,
                                               int* __restrict__ cnt,
                                               float* __restrict__ degw, int E) {
  int e = blockIdx.x * 256 + threadIdx.x;
  if (e < E) {
    int d = dst[e];
    atomicAdd(&cnt[d], 1);
    atomicAdd(&degw[d], w[e]);
  }
}

__global__ __launch_bounds__(1024) void k_scan1(const int* __restrict__ cnt,
                                                int* __restrict__ lscan,
                                                int* __restrict__ bsum, int N) {
  __shared__ int sm[1024];
  int t = threadIdx.x;
  int base = blockIdx.x * 1024;
  int v = (base + t < N) ? cnt[base + t] : 0;
  sm[t] = v;
  __syncthreads();
  for (int off = 1; off < 1024; off <<= 1) {
    int x = (t >= off) ? sm[t - off] : 0;
    __syncthreads();
    sm[t] += x;
    __syncthreads();
  }
  if (base + t < N) lscan[base + t] = sm[t] - v;
  if (t == 1023) bsum[blockIdx.x] = sm[1023];
}

__global__ __launch_bounds__(64) void k_scan2(int* __restrict__ bsum,
                                              int* __restrict__ rowptrN, int nb) {
  if (threadIdx.x == 0) {
    int run = 0;
    for (int i = 0; i < nb; ++i) {
      int v = bsum[i];
      bsum[i] = run;
      run += v;
    }
    *rowptrN = run;
  }
}

__global__ __launch_bounds__(1024) void k_scan3(int* __restrict__ rowptr,
                                                int* __restrict__ cur,
                                                const int* __restrict__ bsum, int N) {
  int i = blockIdx.x * 1024 + threadIdx.x;
  if (i < N) {
    int v = rowptr[i] + bsum[blockIdx.x];
    rowptr[i] = v;
    cur[i] = v;
  }
}

__global__ __launch_bounds__(256) void k_scatter(const int* __restrict__ src,
                                                 const int* __restrict__ dst,
                                                 const float* __restrict__ w,
                                                 int* __restrict__ cur,
                                                 int* __restrict__ srcp,
                                                 float* __restrict__ wp, int E) {
  int e = blockIdx.x * 256 + threadIdx.x;
  if (e < E) {
    int d = dst[e];
    int p = atomicAdd(&cur[d], 1);
    srcp[p] = src[e];
    wp[p] = w[e];
  }
}

// =============================== weight packing ===============================
// W0catT  bf16 [256][128]: rows 0..127: n=h*16+f -> W0[h,k,f]; rows 128..255: gcn_W0[k][n-128]
// logitW  fp32 [128][16] : c<8: va0_src[k][h=c]; c>=8: va0_dst[k][h=c-8]
// gw1T    bf16 [128][128]: gw1T[n][k] = gcn_W1[k][n]
// va1T    bf16 [16][128] : c<8: W1[h=c]@a1_src; c>=8: W1[h]@a1_dst
// WstackT bf16 [128][1024]: WstackT[n][h*128+k] = W1[h][k][n] * 0.125
__global__ __launch_bounds__(256) void k_pack(const float* __restrict__ W0,
                                              const float* __restrict__ a0s,
                                              const float* __restrict__ a0d,
                                              const float* __restrict__ W1,
                                              const float* __restrict__ a1s,
                                              const float* __restrict__ a1d,
                                              const float* __restrict__ gw0,
                                              const float* __restrict__ gw1,
                                              unsigned short* __restrict__ W0catT,
                                              float* __restrict__ logitW,
                                              unsigned short* __restrict__ gw1T,
                                              unsigned short* __restrict__ va1T,
                                              unsigned short* __restrict__ WstackT) {
  int idx = blockIdx.x * 256 + threadIdx.x;
  if (idx < 32768) {
    int n = idx >> 7, k = idx & 127;
    float v;
    if (n < 128) {
      int h = n >> 4, f = n & 15;
      v = W0[h * 2048 + k * 16 + f];
    } else {
      v = gw0[k * 128 + (n - 128)];
    }
    W0catT[idx] = f2bf(v);
  } else if (idx < 34816) {
    int j = idx - 32768;
    int k = j >> 4, c = j & 15;
    int h = (c < 8) ? c : c - 8;
    const float* a = (c < 8) ? a0s : a0d;
    float s = 0.f;
    for (int f = 0; f < 16; ++f) s += W0[h * 2048 + k * 16 + f] * a[h * 16 + f];
    logitW[j] = s;
  } else if (idx < 51200) {
    int j = idx - 34816;
    int n = j >> 7, k = j & 127;
    gw1T[j] = f2bf(gw1[k * 128 + n]);
  } else if (idx < 53248) {
    int j = idx - 51200;
    int c = j >> 7, k = j & 127;
    int h = c & 7;
    const float* a = (c < 8) ? a1s : a1d;
    float s = 0.f;
    for (int f = 0; f < 128; ++f) s += W1[h * 16384 + k * 128 + f] * a[h * 128 + f];
    va1T[j] = f2bf(s);
  } else if (idx < 184320) {
    int j = idx - 53248;
    int n = j >> 10, kk = j & 1023;
    int h = kk >> 7, k = kk & 127;
    WstackT[j] = f2bf(W1[h * 16384 + k * 128 + n] * 0.125f);
  }
}

// cast fp32 -> bf16, 4 elems/thread
__global__ __launch_bounds__(256) void k_cast(const float* __restrict__ x,
                                              unsigned short* __restrict__ xb, int n4) {
  int i = blockIdx.x * 256 + threadIdx.x;
  if (i < n4) {
    float4 v = *(const float4*)(x + (size_t)i * 4);
    ushort4 o;
    o.x = f2bf(v.x); o.y = f2bf(v.y); o.z = f2bf(v.z); o.w = f2bf(v.w);
    *(ushort4*)(xb + (size_t)i * 4) = o;
  }
}

// logit0[N,16] fp32 = x[N,128] @ logitW[128,16]; 16 rows per block
__global__ __launch_bounds__(256) void k_logit0(const float* __restrict__ x,
                                                const float* __restrict__ logitW,
                                                float* __restrict__ logit0, int N) {
  __shared__ float sm[16][132];
  __shared__ float sw[2048];
  int tid = threadIdx.x;
  int base = blockIdx.x * 16;
#pragma unroll
  for (int j = 0; j < 8; ++j) {
    int e = tid + j * 256;
    int r = e >> 7, k = e & 127;
    sm[r][k] = x[(size_t)(base + r) * 128 + k];
    sw[e] = logitW[e];
  }
  __syncthreads();
  int r = tid >> 4, c = tid & 15;
  float acc = 0.f;
#pragma unroll
  for (int k = 0; k < 128; ++k) acc += sm[r][k] * sw[k * 16 + c];
  logit0[(size_t)(base + r) * 16 + c] = acc;
}

// =============================== bf16 MFMA GEMM ===============================
// C[M,Ncols](fp32 or bf16) = A[M,K](bf16) @ BT[Ncols,K](bf16)^T
// tile: 64 rows x NT*16 cols per block; blockIdx.y covers groups of NT*16 cols.
// EPI==1: out = max(acc, aux)
template <int NT, int OUT_BF16, int EPI>
__global__ __launch_bounds__(256) void k_mgemm(const unsigned short* __restrict__ A, int lda,
                                               const unsigned short* __restrict__ BT, int ldb,
                                               void* __restrict__ Cv, int ldc,
                                               const float* __restrict__ aux,
                                               int M, int Ncols, int K) {
  __shared__ unsigned short As[64][64];      // XOR-swizzled in 16B (8-elem) groups
  __shared__ unsigned short Bs[NT * 16][64];
  int tid = threadIdx.x;
  int w = tid >> 6, lane = tid & 63;
  int quad = lane >> 4, l16 = lane & 15;
  int row0 = blockIdx.x * 64;
  int c0 = blockIdx.y * (NT * 16);
  float4v acc[NT];
#pragma unroll
  for (int t = 0; t < NT; ++t) acc[t] = (float4v){0.f, 0.f, 0.f, 0.f};

  for (int k0 = 0; k0 < K; k0 += 64) {
    __syncthreads();
    // stage A: 64 rows x 64 k = 512 chunks of 16B
#pragma unroll
    for (int i = 0; i < 2; ++i) {
      int c = tid + i * 256;
      int r = c >> 3, kc = c & 7;
      uint4 v = {0u, 0u, 0u, 0u};
      int gr = row0 + r;
      if (gr < M) v = *(const uint4*)(A + (size_t)gr * lda + k0 + kc * 8);
      *(uint4*)(&As[r][(kc ^ (r & 7)) * 8]) = v;
    }
    // stage B: NT*16 rows x 64 k
#pragma unroll
    for (int i = 0; i < (NT * 128 + 255) / 256; ++i) {
      int c = tid + i * 256;
      if (c < NT * 128) {
        int n = c >> 3, kc = c & 7;
        uint4 v = {0u, 0u, 0u, 0u};
        int gn = c0 + n;
        if (gn < Ncols) v = *(const uint4*)(BT + (size_t)gn * ldb + k0 + kc * 8);
        *(uint4*)(&Bs[n][(kc ^ (n & 7)) * 8]) = v;
      }
    }
    __syncthreads();
#pragma unroll
    for (int ks = 0; ks < 2; ++ks) {
      int m = w * 16 + l16;
      int ga = (ks * 4 + quad) ^ (m & 7);
      short8 a = *(const short8*)(&As[m][ga * 8]);
#pragma unroll
      for (int t = 0; t < NT; ++t) {
        int n = t * 16 + l16;
        int gb = (ks * 4 + quad) ^ (n & 7);
        short8 b = *(const short8*)(&Bs[n][gb * 8]);
        acc[t] = __builtin_amdgcn_mfma_f32_16x16x32_bf16(a, b, acc[t], 0, 0, 0);
      }
    }
  }
  // epilogue: C/D layout col=lane&15, row=quad*4+reg
#pragma unroll
  for (int t = 0; t < NT; ++t) {
    int cc = c0 + t * 16 + l16;
    if (cc >= Ncols) continue;
#pragma unroll
    for (int i = 0; i < 4; ++i) {
      int rr = row0 + w * 16 + quad * 4 + i;
      if (rr >= M) continue;
      float v = acc[t][i];
      if (EPI) v = fmaxf(v, aux[(size_t)rr * ldc + cc]);
      if (OUT_BF16)
        ((unsigned short*)Cv)[(size_t)rr * ldc + cc] = f2bf(v);
      else
        ((float*)Cv)[(size_t)rr * ldc + cc] = v;
    }
  }
}

// =============================== Phase C: layer-0 aggregation ===============================
// one wave per dst node; lane covers dims {2*lane, 2*lane+1}; head = lane>>3
__global__ __launch_bounds__(256) void k_agg0(const unsigned short* __restrict__ feat0,
                                              const float* __restrict__ logit0,
                                              const int* __restrict__ rowptr,
                                              const int* __restrict__ srcp,
                                              const float* __restrict__ wp,
                                              const float* __restrict__ degw,
                                              unsigned short* __restrict__ x1,
                                              unsigned short* __restrict__ x2, int N) {
  int wave = threadIdx.x >> 6, lane = threadIdx.x & 63;
  int d = blockIdx.x * 4 + wave;
  if (d >= N) return;
  int head = lane >> 3;
  float edv = logit0[(size_t)d * 16 + 8 + head];
  int beg = rowptr[d], end = rowptr[d + 1];
  float l = 0.f, a0 = 0.f, a1 = 0.f, g0 = 0.f, g1 = 0.f;
  for (int i = beg; i < end; ++i) {
    int s = srcp[i];
    float wv = wp[i];
    float es = logit0[(size_t)s * 16 + head];
    unsigned wh = *(const unsigned*)(feat0 + (size_t)s * 256 + 2 * lane);
    unsigned hg = *(const unsigned*)(feat0 + (size_t)s * 256 + 128 + 2 * lane);
    float lg = es + edv;
    lg = lg > 0.f ? lg : LRELU_ALPHA * lg;
    float p = __expf(fminf(lg, 80.f));
    l += p;
    a0 += p * bf2f(wh & 0xffffu);
    a1 += p * bf2f(wh >> 16);
    g0 += wv * bf2f(hg & 0xffffu);
    g1 += wv * bf2f(hg >> 16);
  }
  float inv = l > 0.f ? 1.f / l : 0.f;
  float v0 = a0 * inv, v1 = a1 * inv;
  v0 = v0 > 0.f ? v0 : __expf(v0) - 1.f;  // ELU
  v1 = v1 > 0.f ? v1 : __expf(v1) - 1.f;
  ((unsigned*)x1)[(size_t)d * 64 + lane] = (unsigned)f2bf(v0) | ((unsigned)f2bf(v1) << 16);
  float ginv = 1.f / fmaxf(degw[d], 1e-16f);
  float w0 = fmaxf(g0 * ginv, 0.f), w1 = fmaxf(g1 * ginv, 0.f);
  ((unsigned*)x2)[(size_t)d * 64 + lane] = (unsigned)f2bf(w0) | ((unsigned)f2bf(w1) << 16);
}

// =============================== Phase E: layer-1 aggregation (dst-chunked) ==============
__global__ __launch_bounds__(256) void k_agg1(const unsigned short* __restrict__ x1,
                                              const unsigned short* __restrict__ h1,
                                              const float* __restrict__ esed,
                                              const int* __restrict__ rowptr,
                                              const int* __restrict__ srcp,
                                              const float* __restrict__ wp,
                                              const float* __restrict__ degw,
                                              unsigned short* __restrict__ aggbuf,
                                              float* __restrict__ x2f,
                                              int d0, int d1) {
  int wave = threadIdx.x >> 6, lane = threadIdx.x & 63;
  int d = d0 + blockIdx.x * 4 + wave;
  if (d >= d1) return;
  float ed[8];
#pragma unroll
  for (int h = 0; h < 8; ++h) ed[h] = esed[(size_t)d * 16 + 8 + h];
  int beg = rowptr[d], end = rowptr[d + 1];
  float aggx[8] = {}, aggy[8] = {}, l[8] = {};
  float g0 = 0.f, g1 = 0.f;
  for (int i = beg; i < end; ++i) {
    int s = srcp[i];
    float wv = wp[i];
    unsigned xv = ((const unsigned*)x1)[(size_t)s * 64 + lane];
    unsigned hv = ((const unsigned*)h1)[(size_t)s * 64 + lane];
    float xx = bf2f(xv & 0xffffu), xy = bf2f(xv >> 16);
    g0 += wv * bf2f(hv & 0xffffu);
    g1 += wv * bf2f(hv >> 16);
    const float* esrow = esed + (size_t)s * 16;
#pragma unroll
    for (int h = 0; h < 8; ++h) {
      float lg = esrow[h] + ed[h];
      lg = lg > 0.f ? lg : LRELU_ALPHA * lg;
      float p = __expf(fminf(lg, 80.f));
      l[h] += p;
      aggx[h] += p * xx;
      aggy[h] += p * xy;
    }
  }
  size_t lr = (size_t)(d - d0) * 512;
#pragma unroll
  for (int h = 0; h < 8; ++h) {
    float inv = l[h] > 0.f ? 1.f / l[h] : 0.f;
    ((unsigned*)aggbuf)[lr + h * 64 + lane] =
        (unsigned)f2bf(aggx[h] * inv) | ((unsigned)f2bf(aggy[h] * inv) << 16);
  }
  float ginv = 1.f / fmaxf(degw[d], 1e-16f);
  float w0 = fmaxf(g0 * ginv, 0.f), w1 = fmaxf(g1 * ginv, 0.f);
  *(float2*)(x2f + (size_t)d * 128 + 2 * lane) = make_float2(w0, w1);
}

// =============================== host launch ===============================

extern "C" void kernel_launch(void* const* d_in, const int* in_sizes, int n_in,
                              void* d_out, int out_size, void* d_ws, size_t ws_size,
                              hipStream_t stream) {
  const float* x   = (const float*)d_in[0];
  const int*   ei  = (const int*)d_in[1];
  const float* ew  = (const float*)d_in[2];
  const float* W0  = (const float*)d_in[3];
  const float* a0s = (const float*)d_in[4];
  const float* a0d = (const float*)d_in[5];
  const float* W1  = (const float*)d_in[6];
  const float* a1s = (const float*)d_in[7];
  const float* a1d = (const float*)d_in[8];
  const float* gw0 = (const float*)d_in[9];
  const float* gw1 = (const float*)d_in[10];
  float* out = (float*)d_out;

  const int N = in_sizes[0] / 128;
  const int E = in_sizes[1] / 2;
  const int* src = ei;
  const int* dst = ei + E;

  // workspace carve (256B aligned); peak ~127 MB (proven-safe < round-2's 166 MB)
  char* p = (char*)d_ws;
  auto carve = [&](size_t bytes) {
    void* r = (void*)p;
    p += (bytes + 255) & ~(size_t)255;
    return r;
  };
  int*   cnt    = (int*)carve((size_t)N * 4);
  float* degw   = (float*)carve((size_t)N * 4);
  int*   rowptr = (int*)carve((size_t)(N + 1) * 4);
  int*   cur    = (int*)carve((size_t)N * 4);
  int*   bsum   = (int*)carve(256 * 4);
  int*   srcp   = (int*)carve((size_t)E * 4);
  float* wp     = (float*)carve((size_t)E * 4);
  unsigned short* W0catT  = (unsigned short*)carve(32768 * 2);
  float*          logitW  = (float*)carve(2048 * 4);
  unsigned short* gw1T    = (unsigned short*)carve(16384 * 2);
  unsigned short* va1T    = (unsigned short*)carve(2048 * 2);
  unsigned short* WstackT = (unsigned short*)carve(131072 * 2);
  unsigned short* x1   = (unsigned short*)carve((size_t)N * 128 * 2);
  unsigned short* x2   = (unsigned short*)carve((size_t)N * 128 * 2);
  float*          x2f  = (float*)carve((size_t)N * 128 * 4);
  float*          esed = (float*)carve((size_t)N * 16 * 4);
  unsigned short* h1   = (unsigned short*)carve((size_t)N * 128 * 2);
  // scratch union: {xb, feat0, logit0} then reused as aggbuf
  const int CH = 25600;  // dst-chunk rows (multiple of 64)
  size_t ph1 = ((size_t)N * 128 * 2 + 255) & ~(size_t)255;          // xb
  size_t ph2 = ph1 + (((size_t)N * 256 * 2 + 255) & ~(size_t)255);  // +feat0
  size_t ph3 = ph2 + (((size_t)N * 16 * 4 + 255) & ~(size_t)255);   // +logit0
  size_t scratch_sz = (size_t)CH * 1024 * 2;
  if (ph3 > scratch_sz) scratch_sz = ph3;
  char* scratch = (char*)carve(scratch_sz);
  unsigned short* xb     = (unsigned short*)scratch;
  unsigned short* feat0  = (unsigned short*)(scratch + ph1);
  float*          logit0 = (float*)(scratch + ph2);
  unsigned short* aggbuf = (unsigned short*)scratch;  // alias, live after agg0

  // Phase A: CSR build
  hipMemsetAsync(cnt, 0, (size_t)N * 4, stream);
  hipMemsetAsync(degw, 0, (size_t)N * 4, stream);
  int gE = (E + 255) / 256;
  k_count<<<gE, 256, 0, stream>>>(dst, ew, cnt, degw, E);
  int nb = (N + 1023) / 1024;
  k_scan1<<<nb, 1024, 0, stream>>>(cnt, rowptr, bsum, N);
  k_scan2<<<1, 64, 0, stream>>>(bsum, rowptr + N, nb);
  k_scan3<<<nb, 1024, 0, stream>>>(rowptr, cur, bsum, N);
  k_scatter<<<gE, 256, 0, stream>>>(src, dst, ew, cur, srcp, wp, E);

  // weight packing + x cast + fp32 layer-0 logits
  k_pack<<<(184320 + 255) / 256, 256, 0, stream>>>(W0, a0s, a0d, W1, a1s, a1d, gw0,
                                                   gw1, W0catT, logitW, gw1T, va1T,
                                                   WstackT);
  k_cast<<<((N * 128 / 4) + 255) / 256, 256, 0, stream>>>(x, xb, N * 128 / 4);
  k_logit0<<<N / 16, 256, 0, stream>>>(x, logitW, logit0, N);

  int gM = (N + 63) / 64;
  // Phase B: feat0[N,256] bf16 = xb @ W0catT^T  (cols 0..127 GAT Wh0, 128..255 GCN h0)
  k_mgemm<8, 1, 0><<<dim3(gM, 2), 256, 0, stream>>>(xb, 128, W0catT, 128, feat0, 256,
                                                    nullptr, N, 256, 128);
  // Phase C: layer-0 GAT softmax-agg + ELU -> x1 ; GCN agg + ReLU -> x2 (both bf16)
  k_agg0<<<(N + 3) / 4, 256, 0, stream>>>(feat0, logit0, rowptr, srcp, wp, degw, x1, x2, N);

  // Phase D: esed[N,16] fp32 = x1 @ va1T^T ; h1[N,128] bf16 = x2 @ gw1T^T
  k_mgemm<1, 0, 0><<<dim3(gM, 1), 256, 0, stream>>>(x1, 128, va1T, 128, esed, 16,
                                                    nullptr, N, 16, 128);
  k_mgemm<8, 1, 0><<<dim3(gM, 1), 256, 0, stream>>>(x2, 128, gw1T, 128, h1, 128,
                                                    nullptr, N, 128, 128);

  // Phase E/F: dst-chunked layer-1 aggregation + MFMA output GEMM (max-fused)
  for (int d0 = 0; d0 < N; d0 += CH) {
    int d1 = d0 + CH < N ? d0 + CH : N;
    int chN = d1 - d0;
    k_agg1<<<(chN + 3) / 4, 256, 0, stream>>>(x1, h1, esed, rowptr, srcp, wp, degw,
                                              aggbuf, x2f, d0, d1);
    k_mgemm<8, 0, 1><<<dim3((chN + 63) / 64, 1), 256, 0, stream>>>(
        aggbuf, 1024, WstackT, 1024, out + (size_t)d0 * 128, 128,
        x2f + (size_t)d0 * 128, chN, 128, 1024);
  }
}

// Round 5
// 546.810 us; speedup vs baseline: 2.5177x; 1.1819x over previous
//
#include <hip/hip_runtime.h>

#define LRELU_ALPHA 0.2f

typedef __attribute__((ext_vector_type(8))) short short8;
typedef __attribute__((ext_vector_type(4))) float float4v;

__device__ __forceinline__ unsigned short f2bf(float f) {
  union { float f; unsigned u; } x; x.f = f;
  unsigned r = (x.u + 0x7fff + ((x.u >> 16) & 1)) >> 16;
  return (unsigned short)r;
}
__device__ __forceinline__ float bflo(unsigned u) {
  union { unsigned u; float f; } x; x.u = u << 16; return x.f;
}
__device__ __forceinline__ float bfhi(unsigned u) {
  union { unsigned u; float f; } x; x.u = u & 0xffff0000u; return x.f;
}

// =============================== Phase A: CSR build ===============================

__global__ __launch_bounds__(256) void k_count(const int* __restrict__ dst,
                                               const float* __restrict__ w,
                                               int* __restrict__ cnt,
                                               float* __restrict__ degw, int E) {
  int e = blockIdx.x * 256 + threadIdx.x;
  if (e < E) {
    int d = dst[e];
    atomicAdd(&cnt[d], 1);
    atomicAdd(&degw[d], w[e]);
  }
}

__global__ __launch_bounds__(1024) void k_scan1(const int* __restrict__ cnt,
                                                int* __restrict__ lscan,
                                                int* __restrict__ bsum, int N) {
  __shared__ int sm[1024];
  int t = threadIdx.x;
  int base = blockIdx.x * 1024;
  int v = (base + t < N) ? cnt[base + t] : 0;
  sm[t] = v;
  __syncthreads();
  for (int off = 1; off < 1024; off <<= 1) {
    int x = (t >= off) ? sm[t - off] : 0;
    __syncthreads();
    sm[t] += x;
    __syncthreads();
  }
  if (base + t < N) lscan[base + t] = sm[t] - v;
  if (t == 1023) bsum[blockIdx.x] = sm[1023];
}

__global__ __launch_bounds__(64) void k_scan2(int* __restrict__ bsum,
                                              int* __restrict__ rowptrN, int nb) {
  if (threadIdx.x == 0) {
    int run = 0;
    for (int i = 0; i < nb; ++i) {
      int v = bsum[i];
      bsum[i] = run;
      run += v;
    }
    *rowptrN = run;
  }
}

__global__ __launch_bounds__(1024) void k_scan3(int* __restrict__ rowptr,
                                                int* __restrict__ cur,
                                                const int* __restrict__ bsum, int N) {
  int i = blockIdx.x * 1024 + threadIdx.x;
  if (i < N) {
    int v = rowptr[i] + bsum[blockIdx.x];
    rowptr[i] = v;
    cur[i] = v;
  }
}

__global__ __launch_bounds__(256) void k_scatter(const int* __restrict__ src,
                                                 const int* __restrict__ dst,
                                                 const float* __restrict__ w,
                                                 int* __restrict__ cur,
                                                 int* __restrict__ srcp,
                                                 float* __restrict__ wp, int E) {
  int e = blockIdx.x * 256 + threadIdx.x;
  if (e < E) {
    int d = dst[e];
    int p = atomicAdd(&cur[d], 1);
    srcp[p] = src[e];
    wp[p] = w[e];
  }
}

// =============================== weight packing ===============================
// W0catT bf16 [256][128], ROW-PERMUTED for interleaved feat0i:
//   row n: q=n>>2, r=n&3. r<2 -> GAT col o=2q+r (h=o>>4,f=o&15): W0[h,k,f]
//                        r>=2 -> GCN col j=2q+(r-2): gcn_W0[k][j]
// logitW  fp32 [128][16] : c<8: va0_src[k][h=c]; c>=8: va0_dst[k][h=c-8]
// gw1T    bf16 [128][128]: gw1T[n][k] = gcn_W1[k][n]
// va1T    bf16 [16][128] : c<8: W1[h=c]@a1_src; c>=8: W1[h]@a1_dst
// WstackT bf16 [128][1024]: WstackT[n][h*128+k] = W1[h][k][n] * 0.125
__global__ __launch_bounds__(256) void k_pack(const float* __restrict__ W0,
                                              const float* __restrict__ a0s,
                                              const float* __restrict__ a0d,
                                              const float* __restrict__ W1,
                                              const float* __restrict__ a1s,
                                              const float* __restrict__ a1d,
                                              const float* __restrict__ gw0,
                                              const float* __restrict__ gw1,
                                              unsigned short* __restrict__ W0catT,
                                              float* __restrict__ logitW,
                                              unsigned short* __restrict__ gw1T,
                                              unsigned short* __restrict__ va1T,
                                              unsigned short* __restrict__ WstackT) {
  int idx = blockIdx.x * 256 + threadIdx.x;
  if (idx < 32768) {
    int n = idx >> 7, k = idx & 127;
    int q = n >> 2, r = n & 3;
    float v;
    if (r < 2) {
      int o = 2 * q + r;
      int h = o >> 4, f = o & 15;
      v = W0[h * 2048 + k * 16 + f];
    } else {
      int j = 2 * q + (r - 2);
      v = gw0[k * 128 + j];
    }
    W0catT[idx] = f2bf(v);
  } else if (idx < 34816) {
    int j = idx - 32768;
    int k = j >> 4, c = j & 15;
    int h = (c < 8) ? c : c - 8;
    const float* a = (c < 8) ? a0s : a0d;
    float s = 0.f;
    for (int f = 0; f < 16; ++f) s += W0[h * 2048 + k * 16 + f] * a[h * 16 + f];
    logitW[j] = s;
  } else if (idx < 51200) {
    int j = idx - 34816;
    int n = j >> 7, k = j & 127;
    gw1T[j] = f2bf(gw1[k * 128 + n]);
  } else if (idx < 53248) {
    int j = idx - 51200;
    int c = j >> 7, k = j & 127;
    int h = c & 7;
    const float* a = (c < 8) ? a1s : a1d;
    float s = 0.f;
    for (int f = 0; f < 128; ++f) s += W1[h * 16384 + k * 128 + f] * a[h * 128 + f];
    va1T[j] = f2bf(s);
  } else if (idx < 184320) {
    int j = idx - 53248;
    int n = j >> 10, kk = j & 1023;
    int h = kk >> 7, k = kk & 127;
    WstackT[j] = f2bf(W1[h * 16384 + k * 128 + n] * 0.125f);
  }
}

// fused: xb = bf16(x), logit0[N,16] = x @ logitW; 16 rows per block
__global__ __launch_bounds__(256) void k_prep(const float* __restrict__ x,
                                              const float* __restrict__ logitW,
                                              unsigned short* __restrict__ xb,
                                              float* __restrict__ logit0, int N) {
  __shared__ float sm[16][132];
  __shared__ float sw[2048];
  int t = threadIdx.x;
  int base = blockIdx.x * 16;
  int r = t >> 4, cc = (t & 15) * 8;
  const float* xr = x + (size_t)(base + r) * 128 + cc;
  float4 v0 = *(const float4*)xr;
  float4 v1 = *(const float4*)(xr + 4);
  ushort4 o0 = {f2bf(v0.x), f2bf(v0.y), f2bf(v0.z), f2bf(v0.w)};
  ushort4 o1 = {f2bf(v1.x), f2bf(v1.y), f2bf(v1.z), f2bf(v1.w)};
  *(ushort4*)(xb + (size_t)(base + r) * 128 + cc) = o0;
  *(ushort4*)(xb + (size_t)(base + r) * 128 + cc + 4) = o1;
  *(float4*)&sm[r][cc] = v0;
  *(float4*)&sm[r][cc + 4] = v1;
  *(float4*)&sw[t * 8] = *(const float4*)(logitW + t * 8);
  *(float4*)&sw[t * 8 + 4] = *(const float4*)(logitW + t * 8 + 4);
  __syncthreads();
  int c = t & 15;
  float acc = 0.f;
#pragma unroll
  for (int k = 0; k < 128; ++k) acc += sm[r][k] * sw[k * 16 + c];
  logit0[(size_t)(base + r) * 16 + c] = acc;
}

// =============================== bf16 MFMA GEMM ===============================
// C = A[M,K] @ BT[Ncols,K]^T. EPI: 0 plain, 1 max(acc,aux), 2 interleaved-xh write
template <int NT, int OUT_BF16, int EPI>
__global__ __launch_bounds__(256) void k_mgemm(const unsigned short* __restrict__ A, int lda,
                                               const unsigned short* __restrict__ BT, int ldb,
                                               void* __restrict__ Cv, int ldc,
                                               const float* __restrict__ aux,
                                               int M, int Ncols, int K) {
  __shared__ unsigned short As[64][64];
  __shared__ unsigned short Bs[NT * 16][64];
  int tid = threadIdx.x;
  int w = tid >> 6, lane = tid & 63;
  int quad = lane >> 4, l16 = lane & 15;
  int row0 = blockIdx.x * 64;
  int c0 = blockIdx.y * (NT * 16);
  float4v acc[NT];
#pragma unroll
  for (int t = 0; t < NT; ++t) acc[t] = (float4v){0.f, 0.f, 0.f, 0.f};

  for (int k0 = 0; k0 < K; k0 += 64) {
    __syncthreads();
#pragma unroll
    for (int i = 0; i < 2; ++i) {
      int c = tid + i * 256;
      int r = c >> 3, kc = c & 7;
      uint4 v = {0u, 0u, 0u, 0u};
      int gr = row0 + r;
      if (gr < M) v = *(const uint4*)(A + (size_t)gr * lda + k0 + kc * 8);
      *(uint4*)(&As[r][(kc ^ (r & 7)) * 8]) = v;
    }
#pragma unroll
    for (int i = 0; i < (NT * 128 + 255) / 256; ++i) {
      int c = tid + i * 256;
      if (c < NT * 128) {
        int n = c >> 3, kc = c & 7;
        uint4 v = {0u, 0u, 0u, 0u};
        int gn = c0 + n;
        if (gn < Ncols) v = *(const uint4*)(BT + (size_t)gn * ldb + k0 + kc * 8);
        *(uint4*)(&Bs[n][(kc ^ (n & 7)) * 8]) = v;
      }
    }
    __syncthreads();
#pragma unroll
    for (int ks = 0; ks < 2; ++ks) {
      int m = w * 16 + l16;
      int ga = (ks * 4 + quad) ^ (m & 7);
      short8 a = *(const short8*)(&As[m][ga * 8]);
#pragma unroll
      for (int t = 0; t < NT; ++t) {
        int n = t * 16 + l16;
        int gb = (ks * 4 + quad) ^ (n & 7);
        short8 b = *(const short8*)(&Bs[n][gb * 8]);
        acc[t] = __builtin_amdgcn_mfma_f32_16x16x32_bf16(a, b, acc[t], 0, 0, 0);
      }
    }
  }
#pragma unroll
  for (int t = 0; t < NT; ++t) {
    int cc = c0 + t * 16 + l16;
    if (cc >= Ncols) continue;
#pragma unroll
    for (int i = 0; i < 4; ++i) {
      int rr = row0 + w * 16 + quad * 4 + i;
      if (rr >= M) continue;
      float v = acc[t][i];
      if (EPI == 1) v = fmaxf(v, aux[(size_t)rr * ldc + cc]);
      if (EPI == 2) {
        // h1 -> xh interleaved: col cc -> 4*(cc>>1) + 2 + (cc&1)
        ((unsigned short*)Cv)[(size_t)rr * 256 + 4 * (cc >> 1) + 2 + (cc & 1)] = f2bf(v);
      } else if (OUT_BF16)
        ((unsigned short*)Cv)[(size_t)rr * ldc + cc] = f2bf(v);
      else
        ((float*)Cv)[(size_t)rr * ldc + cc] = v;
    }
  }
}

// =============================== Phase C: layer-0 aggregation ===============================
// wave per dst. feat0i row interleaved: bf16 cols 4q,4q+1 = GAT dims 2q,2q+1;
// 4q+2,4q+3 = GCN dims. lane q covers dims 2q,2q+1 (head=q>>3).
// 64-edge LDS staging; lane j*8+h computes p(edge j, head h); shfl broadcast.
__global__ __launch_bounds__(256) void k_agg0(const unsigned short* __restrict__ feat0i,
                                              const float* __restrict__ logit0,
                                              const int* __restrict__ rowptr,
                                              const int* __restrict__ srcp,
                                              const float* __restrict__ wp,
                                              const float* __restrict__ degw,
                                              unsigned short* __restrict__ x1c,
                                              unsigned short* __restrict__ x2,
                                              unsigned short* __restrict__ xh, int N) {
  __shared__ uint2 swl[4][64];
  int wave = threadIdx.x >> 6, lane = threadIdx.x & 63;
  int d = blockIdx.x * 4 + wave;
  if (d >= N) return;
  int head = lane >> 3, hh = lane & 7, j8 = lane >> 3;
  float edv = logit0[(size_t)d * 16 + 8 + hh];
  int beg = rowptr[d], end = rowptr[d + 1], deg = end - beg;
  float l = 0.f, a0 = 0.f, a1 = 0.f, g0 = 0.f, g1 = 0.f;
  for (int base = 0; base < deg; base += 64) {
    int idx = beg + base + lane;
    int s = 0; float wv = 0.f;
    if (idx < end) { s = srcp[idx]; wv = wp[idx]; }
    swl[wave][lane] = make_uint2((unsigned)s, __float_as_uint(wv));
    int ng = deg - base; if (ng > 64) ng = 64;
    int groups = (ng + 7) >> 3;
    for (int g = 0; g < groups; ++g) {
      uint2 swj = swl[wave][g * 8 + j8];
      float es = logit0[(size_t)swj.x * 16 + hh];
      float lg = es + edv;
      lg = lg > 0.f ? lg : LRELU_ALPHA * lg;
      float pme = __expf(fminf(lg, 80.f));
      if (g * 8 + j8 >= ng) pme = 0.f;
#pragma unroll
      for (int j = 0; j < 8; ++j) {
        uint2 sw = swl[wave][g * 8 + j];
        float pj = __shfl(pme, j * 8 + head, 64);
        float wj = __uint_as_float(sw.y);
        uint2 u = *(const uint2*)(feat0i + (size_t)sw.x * 256 + 4 * lane);
        a0 += pj * bflo(u.x);
        a1 += pj * bfhi(u.x);
        g0 += wj * bflo(u.y);
        g1 += wj * bfhi(u.y);
        l += pj;
      }
    }
  }
  float inv = l > 0.f ? 1.f / l : 0.f;
  float v0 = a0 * inv, v1 = a1 * inv;
  v0 = v0 > 0.f ? v0 : __expf(v0) - 1.f;  // ELU
  v1 = v1 > 0.f ? v1 : __expf(v1) - 1.f;
  unsigned xpack = (unsigned)f2bf(v0) | ((unsigned)f2bf(v1) << 16);
  ((unsigned*)x1c)[(size_t)d * 64 + lane] = xpack;
  ((unsigned*)xh)[(size_t)d * 128 + 2 * lane] = xpack;  // x-pair slot of interleaved row
  float ginv = 1.f / fmaxf(degw[d], 1e-16f);
  float w0 = fmaxf(g0 * ginv, 0.f), w1 = fmaxf(g1 * ginv, 0.f);
  ((unsigned*)x2)[(size_t)d * 64 + lane] = (unsigned)f2bf(w0) | ((unsigned)f2bf(w1) << 16);
}

// =============================== Phase E: layer-1 aggregation (dst-chunked) ==============
// xh row interleaved: 4q,4q+1 = x1 dims 2q,2q+1; 4q+2,4q+3 = h1 dims.
// distributed p: lane j*8+h computes p(edge j, head h), staged in LDS,
// broadcast via float4 same-address LDS reads.
__global__ __launch_bounds__(256) void k_agg1(const unsigned short* __restrict__ xh,
                                              const float* __restrict__ esed,
                                              const int* __restrict__ rowptr,
                                              const int* __restrict__ srcp,
                                              const float* __restrict__ wp,
                                              const float* __restrict__ degw,
                                              unsigned short* __restrict__ aggbuf,
                                              float* __restrict__ x2f,
                                              int d0, int d1) {
  __shared__ uint2 swl[4][64];
  __shared__ float pl[4][64];
  int wave = threadIdx.x >> 6, lane = threadIdx.x & 63;
  int d = d0 + blockIdx.x * 4 + wave;
  if (d >= d1) return;
  int hh = lane & 7, j8 = lane >> 3;
  float ed = esed[(size_t)d * 16 + 8 + hh];
  int beg = rowptr[d], end = rowptr[d + 1], deg = end - beg;
  float ax[8] = {}, ay[8] = {};
  float lpart = 0.f, g0 = 0.f, g1 = 0.f;
  for (int base = 0; base < deg; base += 64) {
    int idx = beg + base + lane;
    int s = 0; float wv = 0.f;
    if (idx < end) { s = srcp[idx]; wv = wp[idx]; }
    swl[wave][lane] = make_uint2((unsigned)s, __float_as_uint(wv));
    int ng = deg - base; if (ng > 64) ng = 64;
    int groups = (ng + 7) >> 3;
    for (int g = 0; g < groups; ++g) {
      uint2 swj = swl[wave][g * 8 + j8];
      float es = esed[(size_t)swj.x * 16 + hh];
      float lg = es + ed;
      lg = lg > 0.f ? lg : LRELU_ALPHA * lg;
      float pme = __expf(fminf(lg, 80.f));
      if (g * 8 + j8 >= ng) pme = 0.f;
      lpart += pme;
      pl[wave][lane] = pme;
#pragma unroll
      for (int j = 0; j < 8; ++j) {
        uint2 sw = swl[wave][g * 8 + j];
        float4 pv0 = *(const float4*)&pl[wave][j * 8];
        float4 pv1 = *(const float4*)&pl[wave][j * 8 + 4];
        uint2 u = *(const uint2*)(xh + (size_t)sw.x * 256 + 4 * lane);
        float xx = bflo(u.x), xy = bfhi(u.x);
        float wj = __uint_as_float(sw.y);
        g0 += wj * bflo(u.y);
        g1 += wj * bfhi(u.y);
        ax[0] += pv0.x * xx; ay[0] += pv0.x * xy;
        ax[1] += pv0.y * xx; ay[1] += pv0.y * xy;
        ax[2] += pv0.z * xx; ay[2] += pv0.z * xy;
        ax[3] += pv0.w * xx; ay[3] += pv0.w * xy;
        ax[4] += pv1.x * xx; ay[4] += pv1.x * xy;
        ax[5] += pv1.y * xx; ay[5] += pv1.y * xy;
        ax[6] += pv1.z * xx; ay[6] += pv1.z * xy;
        ax[7] += pv1.w * xx; ay[7] += pv1.w * xy;
      }
    }
  }
  // head-sum reduce: lanes congruent mod 8 hold partials of head (lane&7)
  lpart += __shfl_xor(lpart, 8, 64);
  lpart += __shfl_xor(lpart, 16, 64);
  lpart += __shfl_xor(lpart, 32, 64);
  size_t lr = (size_t)(d - d0) * 512;
#pragma unroll
  for (int h = 0; h < 8; ++h) {
    float lh = __shfl(lpart, h, 64);
    float inv = lh > 0.f ? 1.f / lh : 0.f;
    ((unsigned*)aggbuf)[lr + h * 64 + lane] =
        (unsigned)f2bf(ax[h] * inv) | ((unsigned)f2bf(ay[h] * inv) << 16);
  }
  float ginv = 1.f / fmaxf(degw[d], 1e-16f);
  float w0 = fmaxf(g0 * ginv, 0.f), w1 = fmaxf(g1 * ginv, 0.f);
  *(float2*)(x2f + (size_t)d * 128 + 2 * lane) = make_float2(w0, w1);
}

// =============================== host launch ===============================

extern "C" void kernel_launch(void* const* d_in, const int* in_sizes, int n_in,
                              void* d_out, int out_size, void* d_ws, size_t ws_size,
                              hipStream_t stream) {
  const float* x   = (const float*)d_in[0];
  const int*   ei  = (const int*)d_in[1];
  const float* ew  = (const float*)d_in[2];
  const float* W0  = (const float*)d_in[3];
  const float* a0s = (const float*)d_in[4];
  const float* a0d = (const float*)d_in[5];
  const float* W1  = (const float*)d_in[6];
  const float* a1s = (const float*)d_in[7];
  const float* a1d = (const float*)d_in[8];
  const float* gw0 = (const float*)d_in[9];
  const float* gw1 = (const float*)d_in[10];
  float* out = (float*)d_out;

  const int N = in_sizes[0] / 128;
  const int E = in_sizes[1] / 2;
  const int* src = ei;
  const int* dst = ei + E;

  // workspace carve (256B aligned); peak ~144 MB (< proven-safe 166 MB)
  char* p = (char*)d_ws;
  auto carve = [&](size_t bytes) {
    void* r = (void*)p;
    p += (bytes + 255) & ~(size_t)255;
    return r;
  };
  int*   cnt    = (int*)carve((size_t)N * 4);
  float* degw   = (float*)carve((size_t)N * 4);
  int*   rowptr = (int*)carve((size_t)(N + 1) * 4);
  int*   cur    = (int*)carve((size_t)N * 4);
  int*   bsum   = (int*)carve(256 * 4);
  int*   srcp   = (int*)carve((size_t)E * 4);
  float* wp     = (float*)carve((size_t)E * 4);
  unsigned short* W0catT  = (unsigned short*)carve(32768 * 2);
  float*          logitW  = (float*)carve(2048 * 4);
  unsigned short* gw1T    = (unsigned short*)carve(16384 * 2);
  unsigned short* va1T    = (unsigned short*)carve(2048 * 2);
  unsigned short* WstackT = (unsigned short*)carve(131072 * 2);
  unsigned short* x1c  = (unsigned short*)carve((size_t)N * 128 * 2);
  unsigned short* x2   = (unsigned short*)carve((size_t)N * 128 * 2);
  float*          x2f  = (float*)carve((size_t)N * 128 * 4);
  float*          esed = (float*)carve((size_t)N * 16 * 4);
  unsigned short* xh   = (unsigned short*)carve((size_t)N * 256 * 2);
  // scratch union: {xb, feat0i, logit0} then reused as aggbuf
  const int CH = 25600;
  size_t ph1 = ((size_t)N * 128 * 2 + 255) & ~(size_t)255;          // xb
  size_t ph2 = ph1 + (((size_t)N * 256 * 2 + 255) & ~(size_t)255);  // +feat0i
  size_t ph3 = ph2 + (((size_t)N * 16 * 4 + 255) & ~(size_t)255);   // +logit0
  size_t scratch_sz = (size_t)CH * 1024 * 2;
  if (ph3 > scratch_sz) scratch_sz = ph3;
  char* scratch = (char*)carve(scratch_sz);
  unsigned short* xb     = (unsigned short*)scratch;
  unsigned short* feat0i = (unsigned short*)(scratch + ph1);
  float*          logit0 = (float*)(scratch + ph2);
  unsigned short* aggbuf = (unsigned short*)scratch;  // alias, live after agg0

  // Phase A: CSR build
  hipMemsetAsync(cnt, 0, (size_t)N * 4, stream);
  hipMemsetAsync(degw, 0, (size_t)N * 4, stream);
  int gE = (E + 255) / 256;
  k_count<<<gE, 256, 0, stream>>>(dst, ew, cnt, degw, E);
  int nb = (N + 1023) / 1024;
  k_scan1<<<nb, 1024, 0, stream>>>(cnt, rowptr, bsum, N);
  k_scan2<<<1, 64, 0, stream>>>(bsum, rowptr + N, nb);
  k_scan3<<<nb, 1024, 0, stream>>>(rowptr, cur, bsum, N);
  k_scatter<<<gE, 256, 0, stream>>>(src, dst, ew, cur, srcp, wp, E);

  // weight packing + fused x-cast/logit0
  k_pack<<<(184320 + 255) / 256, 256, 0, stream>>>(W0, a0s, a0d, W1, a1s, a1d, gw0,
                                                   gw1, W0catT, logitW, gw1T, va1T,
                                                   WstackT);
  k_prep<<<(N + 15) / 16, 256, 0, stream>>>(x, logitW, xb, logit0, N);

  int gM = (N + 63) / 64;
  // Phase B: feat0i[N,256] bf16 (interleaved cols via W0catT row permutation)
  k_mgemm<8, 1, 0><<<dim3(gM, 2), 256, 0, stream>>>(xb, 128, W0catT, 128, feat0i, 256,
                                                    nullptr, N, 256, 128);
  // Phase C: layer-0 GAT softmax-agg + ELU -> x1c & xh ; GCN agg + ReLU -> x2
  k_agg0<<<(N + 3) / 4, 256, 0, stream>>>(feat0i, logit0, rowptr, srcp, wp, degw,
                                          x1c, x2, xh, N);

  // Phase D: esed[N,16] fp32 = x1c @ va1T^T ; h1 = x2 @ gw1T^T -> xh interleaved
  k_mgemm<1, 0, 0><<<dim3(gM, 1), 256, 0, stream>>>(x1c, 128, va1T, 128, esed, 16,
                                                    nullptr, N, 16, 128);
  k_mgemm<8, 1, 2><<<dim3(gM, 1), 256, 0, stream>>>(x2, 128, gw1T, 128, xh, 256,
                                                    nullptr, N, 128, 128);

  // Phase E/F: dst-chunked layer-1 aggregation + MFMA output GEMM (max-fused)
  for (int d0 = 0; d0 < N; d0 += CH) {
    int d1 = d0 + CH < N ? d0 + CH : N;
    int chN = d1 - d0;
    k_agg1<<<(chN + 3) / 4, 256, 0, stream>>>(xh, esed, rowptr, srcp, wp, degw,
                                              aggbuf, x2f, d0, d1);
    k_mgemm<8, 0, 1><<<dim3((chN + 63) / 64, 1), 256, 0, stream>>>(
        aggbuf, 1024, WstackT, 1024, out + (size_t)d0 * 128, 128,
        x2f + (size_t)d0 * 128, chN, 128, 1024);
  }
}

// Round 6
// 499.424 us; speedup vs baseline: 2.7566x; 1.0949x over previous
//
#include <hip/hip_runtime.h>

#define LRELU_ALPHA 0.2f

typedef __attribute__((ext_vector_type(8))) short short8;
typedef __attribute__((ext_vector_type(4))) float float4v;

__device__ __forceinline__ unsigned short f2bf(float f) {
  union { float f; unsigned u; } x; x.f = f;
  unsigned r = (x.u + 0x7fff + ((x.u >> 16) & 1)) >> 16;
  return (unsigned short)r;
}
__device__ __forceinline__ float bflo(unsigned u) {
  union { unsigned u; float f; } x; x.u = u << 16; return x.f;
}
__device__ __forceinline__ float bfhi(unsigned u) {
  union { unsigned u; float f; } x; x.u = u & 0xffff0000u; return x.f;
}

// =============================== Phase A: CSR build ===============================

__global__ __launch_bounds__(256) void k_count(const int* __restrict__ dst,
                                               int* __restrict__ cnt, int E) {
  int e = blockIdx.x * 256 + threadIdx.x;
  if (e < E) atomicAdd(&cnt[dst[e]], 1);
}

__global__ __launch_bounds__(1024) void k_scan1(const int* __restrict__ cnt,
                                                int* __restrict__ lscan,
                                                int* __restrict__ bsum, int N) {
  __shared__ int sm[1024];
  int t = threadIdx.x;
  int base = blockIdx.x * 1024;
  int v = (base + t < N) ? cnt[base + t] : 0;
  sm[t] = v;
  __syncthreads();
  for (int off = 1; off < 1024; off <<= 1) {
    int x = (t >= off) ? sm[t - off] : 0;
    __syncthreads();
    sm[t] += x;
    __syncthreads();
  }
  if (base + t < N) lscan[base + t] = sm[t] - v;
  if (t == 1023) bsum[blockIdx.x] = sm[1023];
}

__global__ __launch_bounds__(64) void k_scan2(int* __restrict__ bsum,
                                              int* __restrict__ rowptrN, int nb) {
  if (threadIdx.x == 0) {
    int run = 0;
    for (int i = 0; i < nb; ++i) {
      int v = bsum[i];
      bsum[i] = run;
      run += v;
    }
    *rowptrN = run;
  }
}

__global__ __launch_bounds__(1024) void k_scan3(int* __restrict__ rowptr,
                                                int* __restrict__ cur,
                                                const int* __restrict__ bsum, int N) {
  int i = blockIdx.x * 1024 + threadIdx.x;
  if (i < N) {
    int v = rowptr[i] + bsum[blockIdx.x];
    rowptr[i] = v;
    cur[i] = v;
  }
}

__global__ __launch_bounds__(256) void k_scatter(const int* __restrict__ src,
                                                 const int* __restrict__ dst,
                                                 const float* __restrict__ w,
                                                 int* __restrict__ cur,
                                                 uint2* __restrict__ edata, int E) {
  int e = blockIdx.x * 256 + threadIdx.x;
  if (e < E) {
    int d = dst[e];
    int p = atomicAdd(&cur[d], 1);
    edata[p] = make_uint2((unsigned)src[e], __float_as_uint(w[e]));
  }
}

// =============================== weight packing ===============================
// W0catT bf16 [256][128], ROW-PERMUTED for interleaved feat0i:
//   row n: q=n>>2, r=n&3. r<2 -> GAT col o=2q+r (h=o>>4,f=o&15): W0[h,k,f]
//                        r>=2 -> GCN col j=2q+(r-2): gcn_W0[k][j]
// logitW  fp32 [128][16] : c<8: va0_src[k][h=c]; c>=8: va0_dst[k][h=c-8]
// gw1T    bf16 [128][128]: gw1T[n][k] = gcn_W1[k][n]
// va1T    bf16 [16][128] : c<8: W1[h=c]@a1_src; c>=8: W1[h]@a1_dst
// WstackT bf16 [128][1024]: WstackT[n][h*128+k] = W1[h][k][n] * 0.125
__global__ __launch_bounds__(256) void k_pack(const float* __restrict__ W0,
                                              const float* __restrict__ a0s,
                                              const float* __restrict__ a0d,
                                              const float* __restrict__ W1,
                                              const float* __restrict__ a1s,
                                              const float* __restrict__ a1d,
                                              const float* __restrict__ gw0,
                                              const float* __restrict__ gw1,
                                              unsigned short* __restrict__ W0catT,
                                              float* __restrict__ logitW,
                                              unsigned short* __restrict__ gw1T,
                                              unsigned short* __restrict__ va1T,
                                              unsigned short* __restrict__ WstackT) {
  int idx = blockIdx.x * 256 + threadIdx.x;
  if (idx < 32768) {
    int n = idx >> 7, k = idx & 127;
    int q = n >> 2, r = n & 3;
    float v;
    if (r < 2) {
      int o = 2 * q + r;
      int h = o >> 4, f = o & 15;
      v = W0[h * 2048 + k * 16 + f];
    } else {
      int j = 2 * q + (r - 2);
      v = gw0[k * 128 + j];
    }
    W0catT[idx] = f2bf(v);
  } else if (idx < 34816) {
    int j = idx - 32768;
    int k = j >> 4, c = j & 15;
    int h = (c < 8) ? c : c - 8;
    const float* a = (c < 8) ? a0s : a0d;
    float s = 0.f;
    for (int f = 0; f < 16; ++f) s += W0[h * 2048 + k * 16 + f] * a[h * 16 + f];
    logitW[j] = s;
  } else if (idx < 51200) {
    int j = idx - 34816;
    int n = j >> 7, k = j & 127;
    gw1T[j] = f2bf(gw1[k * 128 + n]);
  } else if (idx < 53248) {
    int j = idx - 51200;
    int c = j >> 7, k = j & 127;
    int h = c & 7;
    const float* a = (c < 8) ? a1s : a1d;
    float s = 0.f;
    for (int f = 0; f < 128; ++f) s += W1[h * 16384 + k * 128 + f] * a[h * 128 + f];
    va1T[j] = f2bf(s);
  } else if (idx < 184320) {
    int j = idx - 53248;
    int n = j >> 10, kk = j & 1023;
    int h = kk >> 7, k = kk & 127;
    WstackT[j] = f2bf(W1[h * 16384 + k * 128 + n] * 0.125f);
  }
}

// fused: xb = bf16(x), logit0[N,16] = x @ logitW; 16 rows per block
__global__ __launch_bounds__(256) void k_prep(const float* __restrict__ x,
                                              const float* __restrict__ logitW,
                                              unsigned short* __restrict__ xb,
                                              float* __restrict__ logit0, int N) {
  __shared__ float sm[16][132];
  __shared__ float sw[2048];
  int t = threadIdx.x;
  int base = blockIdx.x * 16;
  int r = t >> 4, cc = (t & 15) * 8;
  const float* xr = x + (size_t)(base + r) * 128 + cc;
  float4 v0 = *(const float4*)xr;
  float4 v1 = *(const float4*)(xr + 4);
  ushort4 o0 = {f2bf(v0.x), f2bf(v0.y), f2bf(v0.z), f2bf(v0.w)};
  ushort4 o1 = {f2bf(v1.x), f2bf(v1.y), f2bf(v1.z), f2bf(v1.w)};
  *(ushort4*)(xb + (size_t)(base + r) * 128 + cc) = o0;
  *(ushort4*)(xb + (size_t)(base + r) * 128 + cc + 4) = o1;
  *(float4*)&sm[r][cc] = v0;
  *(float4*)&sm[r][cc + 4] = v1;
  *(float4*)&sw[t * 8] = *(const float4*)(logitW + t * 8);
  *(float4*)&sw[t * 8 + 4] = *(const float4*)(logitW + t * 8 + 4);
  __syncthreads();
  int c = t & 15;
  float acc = 0.f;
#pragma unroll
  for (int k = 0; k < 128; ++k) acc += sm[r][k] * sw[k * 16 + c];
  logit0[(size_t)(base + r) * 16 + c] = acc;
}

// =============================== bf16 MFMA GEMM ===============================
// C = A[M,K] @ BT[Ncols,K]^T. EPI: 0 plain, 1 max(acc,aux), 2 interleaved-xh write
template <int NT, int OUT_BF16, int EPI>
__global__ __launch_bounds__(256) void k_mgemm(const unsigned short* __restrict__ A, int lda,
                                               const unsigned short* __restrict__ BT, int ldb,
                                               void* __restrict__ Cv, int ldc,
                                               const float* __restrict__ aux,
                                               int M, int Ncols, int K) {
  __shared__ unsigned short As[64][64];
  __shared__ unsigned short Bs[NT * 16][64];
  int tid = threadIdx.x;
  int w = tid >> 6, lane = tid & 63;
  int quad = lane >> 4, l16 = lane & 15;
  int row0 = blockIdx.x * 64;
  int c0 = blockIdx.y * (NT * 16);
  float4v acc[NT];
#pragma unroll
  for (int t = 0; t < NT; ++t) acc[t] = (float4v){0.f, 0.f, 0.f, 0.f};

  for (int k0 = 0; k0 < K; k0 += 64) {
    __syncthreads();
#pragma unroll
    for (int i = 0; i < 2; ++i) {
      int c = tid + i * 256;
      int r = c >> 3, kc = c & 7;
      uint4 v = {0u, 0u, 0u, 0u};
      int gr = row0 + r;
      if (gr < M) v = *(const uint4*)(A + (size_t)gr * lda + k0 + kc * 8);
      *(uint4*)(&As[r][(kc ^ (r & 7)) * 8]) = v;
    }
#pragma unroll
    for (int i = 0; i < (NT * 128 + 255) / 256; ++i) {
      int c = tid + i * 256;
      if (c < NT * 128) {
        int n = c >> 3, kc = c & 7;
        uint4 v = {0u, 0u, 0u, 0u};
        int gn = c0 + n;
        if (gn < Ncols) v = *(const uint4*)(BT + (size_t)gn * ldb + k0 + kc * 8);
        *(uint4*)(&Bs[n][(kc ^ (n & 7)) * 8]) = v;
      }
    }
    __syncthreads();
#pragma unroll
    for (int ks = 0; ks < 2; ++ks) {
      int m = w * 16 + l16;
      int ga = (ks * 4 + quad) ^ (m & 7);
      short8 a = *(const short8*)(&As[m][ga * 8]);
#pragma unroll
      for (int t = 0; t < NT; ++t) {
        int n = t * 16 + l16;
        int gb = (ks * 4 + quad) ^ (n & 7);
        short8 b = *(const short8*)(&Bs[n][gb * 8]);
        acc[t] = __builtin_amdgcn_mfma_f32_16x16x32_bf16(a, b, acc[t], 0, 0, 0);
      }
    }
  }
#pragma unroll
  for (int t = 0; t < NT; ++t) {
    int cc = c0 + t * 16 + l16;
    if (cc >= Ncols) continue;
#pragma unroll
    for (int i = 0; i < 4; ++i) {
      int rr = row0 + w * 16 + quad * 4 + i;
      if (rr >= M) continue;
      float v = acc[t][i];
      if (EPI == 1) v = fmaxf(v, aux[(size_t)rr * ldc + cc]);
      if (EPI == 2) {
        // h1 -> xh interleaved: col cc -> 4*(cc>>1) + 2 + (cc&1)
        ((unsigned short*)Cv)[(size_t)rr * 256 + 4 * (cc >> 1) + 2 + (cc & 1)] = f2bf(v);
      } else if (OUT_BF16)
        ((unsigned short*)Cv)[(size_t)rr * ldc + cc] = f2bf(v);
      else
        ((float*)Cv)[(size_t)rr * ldc + cc] = v;
    }
  }
}

// =============================== Phase C: layer-0 aggregation ===============================
// wave per dst. feat0i row interleaved: bf16 cols 4q,4q+1 = GAT dims 2q,2q+1;
// 4q+2,4q+3 = GCN dims. lane q covers dims 2q,2q+1 (head=q>>3).
// degw computed locally (every lane sees every edge's w; pad edges have w=0).
__global__ __launch_bounds__(256) void k_agg0(const unsigned short* __restrict__ feat0i,
                                              const float* __restrict__ logit0,
                                              const int* __restrict__ rowptr,
                                              const uint2* __restrict__ edata,
                                              unsigned short* __restrict__ x1c,
                                              unsigned short* __restrict__ x2,
                                              unsigned short* __restrict__ xh, int N) {
  __shared__ uint2 swl[4][64];
  int wave = threadIdx.x >> 6, lane = threadIdx.x & 63;
  int d = blockIdx.x * 4 + wave;
  if (d >= N) return;
  int head = lane >> 3, hh = lane & 7, j8 = lane >> 3;
  float edv = logit0[(size_t)d * 16 + 8 + hh];
  int beg = rowptr[d], end = rowptr[d + 1], deg = end - beg;
  float l = 0.f, a0 = 0.f, a1 = 0.f, g0 = 0.f, g1 = 0.f, wsum = 0.f;
  for (int base = 0; base < deg; base += 64) {
    int idx = beg + base + lane;
    uint2 sv = make_uint2(0u, 0u);
    if (idx < end) sv = edata[idx];
    swl[wave][lane] = sv;
    int ng = deg - base; if (ng > 64) ng = 64;
    int groups = (ng + 7) >> 3;
    for (int g = 0; g < groups; ++g) {
      uint2 swj = swl[wave][g * 8 + j8];
      float es = logit0[(size_t)swj.x * 16 + hh];
      float lg = es + edv;
      lg = lg > 0.f ? lg : LRELU_ALPHA * lg;
      float pme = __expf(fminf(lg, 80.f));
      if (g * 8 + j8 >= ng) pme = 0.f;
#pragma unroll
      for (int j = 0; j < 8; ++j) {
        uint2 sw = swl[wave][g * 8 + j];
        float pj = __shfl(pme, j * 8 + head, 64);
        float wj = __uint_as_float(sw.y);
        uint2 u = *(const uint2*)(feat0i + (size_t)sw.x * 256 + 4 * lane);
        a0 += pj * bflo(u.x);
        a1 += pj * bfhi(u.x);
        g0 += wj * bflo(u.y);
        g1 += wj * bfhi(u.y);
        l += pj;
        wsum += wj;
      }
    }
  }
  float inv = l > 0.f ? 1.f / l : 0.f;
  float v0 = a0 * inv, v1 = a1 * inv;
  v0 = v0 > 0.f ? v0 : __expf(v0) - 1.f;  // ELU
  v1 = v1 > 0.f ? v1 : __expf(v1) - 1.f;
  unsigned xpack = (unsigned)f2bf(v0) | ((unsigned)f2bf(v1) << 16);
  ((unsigned*)x1c)[(size_t)d * 64 + lane] = xpack;
  ((unsigned*)xh)[(size_t)d * 128 + 2 * lane] = xpack;  // x-pair slot of interleaved row
  float ginv = 1.f / fmaxf(wsum, 1e-16f);
  float w0 = fmaxf(g0 * ginv, 0.f), w1 = fmaxf(g1 * ginv, 0.f);
  ((unsigned*)x2)[(size_t)d * 64 + lane] = (unsigned)f2bf(w0) | ((unsigned)f2bf(w1) << 16);
}

// =============================== Phase E: layer-1 aggregation (dst-chunked) ==============
// xh row interleaved: 4q,4q+1 = x1 dims 2q,2q+1; 4q+2,4q+3 = h1 dims.
// distributed p: lane j*8+h computes p(edge j, head h), staged in LDS,
// broadcast via float4 same-address LDS reads. degw computed locally.
__global__ __launch_bounds__(256) void k_agg1(const unsigned short* __restrict__ xh,
                                              const float* __restrict__ esed,
                                              const int* __restrict__ rowptr,
                                              const uint2* __restrict__ edata,
                                              unsigned short* __restrict__ aggbuf,
                                              float* __restrict__ x2f,
                                              int d0, int d1) {
  __shared__ uint2 swl[4][64];
  __shared__ float pl[4][64];
  int wave = threadIdx.x >> 6, lane = threadIdx.x & 63;
  int d = d0 + blockIdx.x * 4 + wave;
  if (d >= d1) return;
  int hh = lane & 7, j8 = lane >> 3;
  float ed = esed[(size_t)d * 16 + 8 + hh];
  int beg = rowptr[d], end = rowptr[d + 1], deg = end - beg;
  float ax[8] = {}, ay[8] = {};
  float lpart = 0.f, g0 = 0.f, g1 = 0.f, wsum = 0.f;
  for (int base = 0; base < deg; base += 64) {
    int idx = beg + base + lane;
    uint2 sv = make_uint2(0u, 0u);
    if (idx < end) sv = edata[idx];
    swl[wave][lane] = sv;
    int ng = deg - base; if (ng > 64) ng = 64;
    int groups = (ng + 7) >> 3;
    for (int g = 0; g < groups; ++g) {
      uint2 swj = swl[wave][g * 8 + j8];
      float es = esed[(size_t)swj.x * 16 + hh];
      float lg = es + ed;
      lg = lg > 0.f ? lg : LRELU_ALPHA * lg;
      float pme = __expf(fminf(lg, 80.f));
      if (g * 8 + j8 >= ng) pme = 0.f;
      lpart += pme;
      pl[wave][lane] = pme;
#pragma unroll
      for (int j = 0; j < 8; ++j) {
        uint2 sw = swl[wave][g * 8 + j];
        float4 pv0 = *(const float4*)&pl[wave][j * 8];
        float4 pv1 = *(const float4*)&pl[wave][j * 8 + 4];
        uint2 u = *(const uint2*)(xh + (size_t)sw.x * 256 + 4 * lane);
        float xx = bflo(u.x), xy = bfhi(u.x);
        float wj = __uint_as_float(sw.y);
        g0 += wj * bflo(u.y);
        g1 += wj * bfhi(u.y);
        wsum += wj;
        ax[0] += pv0.x * xx; ay[0] += pv0.x * xy;
        ax[1] += pv0.y * xx; ay[1] += pv0.y * xy;
        ax[2] += pv0.z * xx; ay[2] += pv0.z * xy;
        ax[3] += pv0.w * xx; ay[3] += pv0.w * xy;
        ax[4] += pv1.x * xx; ay[4] += pv1.x * xy;
        ax[5] += pv1.y * xx; ay[5] += pv1.y * xy;
        ax[6] += pv1.z * xx; ay[6] += pv1.z * xy;
        ax[7] += pv1.w * xx; ay[7] += pv1.w * xy;
      }
    }
  }
  // head-sum reduce: lanes congruent mod 8 hold partials of head (lane&7)
  lpart += __shfl_xor(lpart, 8, 64);
  lpart += __shfl_xor(lpart, 16, 64);
  lpart += __shfl_xor(lpart, 32, 64);
  size_t lr = (size_t)(d - d0) * 512;
#pragma unroll
  for (int h = 0; h < 8; ++h) {
    float lh = __shfl(lpart, h, 64);
    float inv = lh > 0.f ? 1.f / lh : 0.f;
    ((unsigned*)aggbuf)[lr + h * 64 + lane] =
        (unsigned)f2bf(ax[h] * inv) | ((unsigned)f2bf(ay[h] * inv) << 16);
  }
  float ginv = 1.f / fmaxf(wsum, 1e-16f);
  float w0 = fmaxf(g0 * ginv, 0.f), w1 = fmaxf(g1 * ginv, 0.f);
  *(float2*)(x2f + (size_t)d * 128 + 2 * lane) = make_float2(w0, w1);
}

// =============================== host launch ===============================

extern "C" void kernel_launch(void* const* d_in, const int* in_sizes, int n_in,
                              void* d_out, int out_size, void* d_ws, size_t ws_size,
                              hipStream_t stream) {
  const float* x   = (const float*)d_in[0];
  const int*   ei  = (const int*)d_in[1];
  const float* ew  = (const float*)d_in[2];
  const float* W0  = (const float*)d_in[3];
  const float* a0s = (const float*)d_in[4];
  const float* a0d = (const float*)d_in[5];
  const float* W1  = (const float*)d_in[6];
  const float* a1s = (const float*)d_in[7];
  const float* a1d = (const float*)d_in[8];
  const float* gw0 = (const float*)d_in[9];
  const float* gw1 = (const float*)d_in[10];
  float* out = (float*)d_out;

  const int N = in_sizes[0] / 128;
  const int E = in_sizes[1] / 2;
  const int* src = ei;
  const int* dst = ei + E;

  // workspace carve (256B aligned); peak ~144 MB (< proven-safe 166 MB)
  char* p = (char*)d_ws;
  auto carve = [&](size_t bytes) {
    void* r = (void*)p;
    p += (bytes + 255) & ~(size_t)255;
    return r;
  };
  int*   cnt    = (int*)carve((size_t)N * 4);
  int*   rowptr = (int*)carve((size_t)(N + 1) * 4);
  int*   cur    = (int*)carve((size_t)N * 4);
  int*   bsum   = (int*)carve(256 * 4);
  uint2* edata  = (uint2*)carve((size_t)E * 8);
  unsigned short* W0catT  = (unsigned short*)carve(32768 * 2);
  float*          logitW  = (float*)carve(2048 * 4);
  unsigned short* gw1T    = (unsigned short*)carve(16384 * 2);
  unsigned short* va1T    = (unsigned short*)carve(2048 * 2);
  unsigned short* WstackT = (unsigned short*)carve(131072 * 2);
  unsigned short* x1c  = (unsigned short*)carve((size_t)N * 128 * 2);
  unsigned short* x2   = (unsigned short*)carve((size_t)N * 128 * 2);
  float*          x2f  = (float*)carve((size_t)N * 128 * 4);
  float*          esed = (float*)carve((size_t)N * 16 * 4);
  unsigned short* xh   = (unsigned short*)carve((size_t)N * 256 * 2);
  // scratch union: {xb, feat0i, logit0} then reused as aggbuf
  const int CH = 25600;
  size_t ph1 = ((size_t)N * 128 * 2 + 255) & ~(size_t)255;          // xb
  size_t ph2 = ph1 + (((size_t)N * 256 * 2 + 255) & ~(size_t)255);  // +feat0i
  size_t ph3 = ph2 + (((size_t)N * 16 * 4 + 255) & ~(size_t)255);   // +logit0
  size_t scratch_sz = (size_t)CH * 1024 * 2;
  if (ph3 > scratch_sz) scratch_sz = ph3;
  char* scratch = (char*)carve(scratch_sz);
  unsigned short* xb     = (unsigned short*)scratch;
  unsigned short* feat0i = (unsigned short*)(scratch + ph1);
  float*          logit0 = (float*)(scratch + ph2);
  unsigned short* aggbuf = (unsigned short*)scratch;  // alias, live after agg0

  // Phase A: CSR build (single int atomic; no float atomics anywhere)
  hipMemsetAsync(cnt, 0, (size_t)N * 4, stream);
  int gE = (E + 255) / 256;
  k_count<<<gE, 256, 0, stream>>>(dst, cnt, E);
  int nb = (N + 1023) / 1024;
  k_scan1<<<nb, 1024, 0, stream>>>(cnt, rowptr, bsum, N);
  k_scan2<<<1, 64, 0, stream>>>(bsum, rowptr + N, nb);
  k_scan3<<<nb, 1024, 0, stream>>>(rowptr, cur, bsum, N);
  k_scatter<<<gE, 256, 0, stream>>>(src, dst, ew, cur, edata, E);

  // weight packing + fused x-cast/logit0
  k_pack<<<(184320 + 255) / 256, 256, 0, stream>>>(W0, a0s, a0d, W1, a1s, a1d, gw0,
                                                   gw1, W0catT, logitW, gw1T, va1T,
                                                   WstackT);
  k_prep<<<(N + 15) / 16, 256, 0, stream>>>(x, logitW, xb, logit0, N);

  int gM = (N + 63) / 64;
  // Phase B: feat0i[N,256] bf16 (interleaved cols via W0catT row permutation)
  k_mgemm<8, 1, 0><<<dim3(gM, 2), 256, 0, stream>>>(xb, 128, W0catT, 128, feat0i, 256,
                                                    nullptr, N, 256, 128);
  // Phase C: layer-0 GAT softmax-agg + ELU -> x1c & xh ; GCN agg + ReLU -> x2
  k_agg0<<<(N + 3) / 4, 256, 0, stream>>>(feat0i, logit0, rowptr, edata,
                                          x1c, x2, xh, N);

  // Phase D: esed[N,16] fp32 = x1c @ va1T^T ; h1 = x2 @ gw1T^T -> xh interleaved
  k_mgemm<1, 0, 0><<<dim3(gM, 1), 256, 0, stream>>>(x1c, 128, va1T, 128, esed, 16,
                                                    nullptr, N, 16, 128);
  k_mgemm<8, 1, 2><<<dim3(gM, 1), 256, 0, stream>>>(x2, 128, gw1T, 128, xh, 256,
                                                    nullptr, N, 128, 128);

  // Phase E/F: dst-chunked layer-1 aggregation + MFMA output GEMM (max-fused)
  for (int d0 = 0; d0 < N; d0 += CH) {
    int d1 = d0 + CH < N ? d0 + CH : N;
    int chN = d1 - d0;
    k_agg1<<<(chN + 3) / 4, 256, 0, stream>>>(xh, esed, rowptr, edata,
                                              aggbuf, x2f, d0, d1);
    k_mgemm<8, 0, 1><<<dim3((chN + 63) / 64, 1), 256, 0, stream>>>(
        aggbuf, 1024, WstackT, 1024, out + (size_t)d0 * 128, 128,
        x2f + (size_t)d0 * 128, chN, 128, 1024);
  }
}

// Round 7
// 487.956 us; speedup vs baseline: 2.8213x; 1.0235x over previous
//
#include <hip/hip_runtime.h>

#define LRELU_ALPHA 0.2f

typedef __attribute__((ext_vector_type(8))) short short8;
typedef __attribute__((ext_vector_type(4))) float float4v;
typedef __attribute__((ext_vector_type(2))) float f32x2;

__device__ __forceinline__ unsigned short f2bf(float f) {
  union { float f; unsigned u; } x; x.f = f;
  unsigned r = (x.u + 0x7fff + ((x.u >> 16) & 1)) >> 16;
  return (unsigned short)r;
}
__device__ __forceinline__ float bflo(unsigned u) {
  union { unsigned u; float f; } x; x.u = u << 16; return x.f;
}
__device__ __forceinline__ float bfhi(unsigned u) {
  union { unsigned u; float f; } x; x.u = u & 0xffff0000u; return x.f;
}
__device__ __forceinline__ f32x2 bfpair(unsigned u) {
  return (f32x2){bflo(u), bfhi(u)};
}

// =============================== Phase A: CSR build ===============================

__global__ __launch_bounds__(256) void k_count(const int* __restrict__ dst,
                                               int* __restrict__ cnt, int E) {
  int e = blockIdx.x * 256 + threadIdx.x;
  if (e < E) atomicAdd(&cnt[dst[e]], 1);
}

__global__ __launch_bounds__(1024) void k_scan1(const int* __restrict__ cnt,
                                                int* __restrict__ lscan,
                                                int* __restrict__ bsum, int N) {
  __shared__ int sm[1024];
  int t = threadIdx.x;
  int base = blockIdx.x * 1024;
  int v = (base + t < N) ? cnt[base + t] : 0;
  sm[t] = v;
  __syncthreads();
  for (int off = 1; off < 1024; off <<= 1) {
    int x = (t >= off) ? sm[t - off] : 0;
    __syncthreads();
    sm[t] += x;
    __syncthreads();
  }
  if (base + t < N) lscan[base + t] = sm[t] - v;
  if (t == 1023) bsum[blockIdx.x] = sm[1023];
}

// one-wave shfl scan (nb <= 64)
__global__ __launch_bounds__(64) void k_scan2(int* __restrict__ bsum,
                                              int* __restrict__ rowptrN, int nb) {
  int t = threadIdx.x;
  int v = (t < nb) ? bsum[t] : 0;
  int orig = v;
  for (int off = 1; off < 64; off <<= 1) {
    int y = __shfl_up(v, off, 64);
    if (t >= off) v += y;
  }
  if (t < nb) bsum[t] = v - orig;
  if (t == 63) *rowptrN = v;
}

__global__ __launch_bounds__(1024) void k_scan3(int* __restrict__ rowptr,
                                                int* __restrict__ cur,
                                                const int* __restrict__ bsum, int N) {
  int i = blockIdx.x * 1024 + threadIdx.x;
  if (i < N) {
    int v = rowptr[i] + bsum[blockIdx.x];
    rowptr[i] = v;
    cur[i] = v;
  }
}

__global__ __launch_bounds__(256) void k_scatter(const int* __restrict__ src,
                                                 const int* __restrict__ dst,
                                                 const float* __restrict__ w,
                                                 int* __restrict__ cur,
                                                 uint2* __restrict__ edata, int E) {
  int e = blockIdx.x * 256 + threadIdx.x;
  if (e < E) {
    int d = dst[e];
    int p = atomicAdd(&cur[d], 1);
    edata[p] = make_uint2((unsigned)src[e], __float_as_uint(w[e]));
  }
}

// =============================== weight packing ===============================
// W0catT bf16 [256][128], ROW-PERMUTED for interleaved feat0i:
//   row n: q=n>>2, r=n&3. r<2 -> GAT col o=2q+r (h=o>>4,f=o&15): W0[h,k,f]
//                        r>=2 -> GCN col j=2q+(r-2): gcn_W0[k][j]
// logitW  fp32 [128][16] : c<8: va0_src[k][h=c]; c>=8: va0_dst[k][h=c-8]
// gw1T    bf16 [128][128]: gw1T[n][k] = gcn_W1[k][n]
// va1T    bf16 [16][128] : c<8: W1[h=c]@a1_src; c>=8: W1[h]@a1_dst
// WstackT bf16 [128][1024]: WstackT[n][h*128+k] = W1[h][k][n] * 0.125
__global__ __launch_bounds__(256) void k_pack(const float* __restrict__ W0,
                                              const float* __restrict__ a0s,
                                              const float* __restrict__ a0d,
                                              const float* __restrict__ W1,
                                              const float* __restrict__ a1s,
                                              const float* __restrict__ a1d,
                                              const float* __restrict__ gw0,
                                              const float* __restrict__ gw1,
                                              unsigned short* __restrict__ W0catT,
                                              float* __restrict__ logitW,
                                              unsigned short* __restrict__ gw1T,
                                              unsigned short* __restrict__ va1T,
                                              unsigned short* __restrict__ WstackT) {
  int idx = blockIdx.x * 256 + threadIdx.x;
  if (idx < 32768) {
    int n = idx >> 7, k = idx & 127;
    int q = n >> 2, r = n & 3;
    float v;
    if (r < 2) {
      int o = 2 * q + r;
      int h = o >> 4, f = o & 15;
      v = W0[h * 2048 + k * 16 + f];
    } else {
      int j = 2 * q + (r - 2);
      v = gw0[k * 128 + j];
    }
    W0catT[idx] = f2bf(v);
  } else if (idx < 34816) {
    int j = idx - 32768;
    int k = j >> 4, c = j & 15;
    int h = (c < 8) ? c : c - 8;
    const float* a = (c < 8) ? a0s : a0d;
    float s = 0.f;
    for (int f = 0; f < 16; ++f) s += W0[h * 2048 + k * 16 + f] * a[h * 16 + f];
    logitW[j] = s;
  } else if (idx < 51200) {
    int j = idx - 34816;
    int n = j >> 7, k = j & 127;
    gw1T[j] = f2bf(gw1[k * 128 + n]);
  } else if (idx < 53248) {
    int j = idx - 51200;
    int c = j >> 7, k = j & 127;
    int h = c & 7;
    const float* a = (c < 8) ? a1s : a1d;
    float s = 0.f;
    for (int f = 0; f < 128; ++f) s += W1[h * 16384 + k * 128 + f] * a[h * 128 + f];
    va1T[j] = f2bf(s);
  } else if (idx < 184320) {
    int j = idx - 53248;
    int n = j >> 10, kk = j & 1023;
    int h = kk >> 7, k = kk & 127;
    WstackT[j] = f2bf(W1[h * 16384 + k * 128 + n] * 0.125f);
  }
}

// fused: xb = bf16(x), logit0[N,16] = x @ logitW; 16 rows per block
__global__ __launch_bounds__(256) void k_prep(const float* __restrict__ x,
                                              const float* __restrict__ logitW,
                                              unsigned short* __restrict__ xb,
                                              float* __restrict__ logit0, int N) {
  __shared__ float sm[16][132];
  __shared__ float sw[2048];
  int t = threadIdx.x;
  int base = blockIdx.x * 16;
  int r = t >> 4, cc = (t & 15) * 8;
  const float* xr = x + (size_t)(base + r) * 128 + cc;
  float4 v0 = *(const float4*)xr;
  float4 v1 = *(const float4*)(xr + 4);
  ushort4 o0 = {f2bf(v0.x), f2bf(v0.y), f2bf(v0.z), f2bf(v0.w)};
  ushort4 o1 = {f2bf(v1.x), f2bf(v1.y), f2bf(v1.z), f2bf(v1.w)};
  *(ushort4*)(xb + (size_t)(base + r) * 128 + cc) = o0;
  *(ushort4*)(xb + (size_t)(base + r) * 128 + cc + 4) = o1;
  *(float4*)&sm[r][cc] = v0;
  *(float4*)&sm[r][cc + 4] = v1;
  *(float4*)&sw[t * 8] = *(const float4*)(logitW + t * 8);
  *(float4*)&sw[t * 8 + 4] = *(const float4*)(logitW + t * 8 + 4);
  __syncthreads();
  int c = t & 15;
  float acc = 0.f;
#pragma unroll
  for (int k = 0; k < 128; ++k) acc += sm[r][k] * sw[k * 16 + c];
  logit0[(size_t)(base + r) * 16 + c] = acc;
}

// =============================== bf16 MFMA GEMM ===============================
// C = A[M,K] @ BT[Ncols,K]^T. EPI: 0 plain, 1 max(acc, bf16 aux), 2 interleaved-xh write
template <int NT, int OUT_BF16, int EPI>
__global__ __launch_bounds__(256) void k_mgemm(const unsigned short* __restrict__ A, int lda,
                                               const unsigned short* __restrict__ BT, int ldb,
                                               void* __restrict__ Cv, int ldc,
                                               const void* __restrict__ aux,
                                               int M, int Ncols, int K) {
  __shared__ unsigned short As[64][64];
  __shared__ unsigned short Bs[NT * 16][64];
  int tid = threadIdx.x;
  int w = tid >> 6, lane = tid & 63;
  int quad = lane >> 4, l16 = lane & 15;
  int row0 = blockIdx.x * 64;
  int c0 = blockIdx.y * (NT * 16);
  float4v acc[NT];
#pragma unroll
  for (int t = 0; t < NT; ++t) acc[t] = (float4v){0.f, 0.f, 0.f, 0.f};

  for (int k0 = 0; k0 < K; k0 += 64) {
    __syncthreads();
#pragma unroll
    for (int i = 0; i < 2; ++i) {
      int c = tid + i * 256;
      int r = c >> 3, kc = c & 7;
      uint4 v = {0u, 0u, 0u, 0u};
      int gr = row0 + r;
      if (gr < M) v = *(const uint4*)(A + (size_t)gr * lda + k0 + kc * 8);
      *(uint4*)(&As[r][(kc ^ (r & 7)) * 8]) = v;
    }
#pragma unroll
    for (int i = 0; i < (NT * 128 + 255) / 256; ++i) {
      int c = tid + i * 256;
      if (c < NT * 128) {
        int n = c >> 3, kc = c & 7;
        uint4 v = {0u, 0u, 0u, 0u};
        int gn = c0 + n;
        if (gn < Ncols) v = *(const uint4*)(BT + (size_t)gn * ldb + k0 + kc * 8);
        *(uint4*)(&Bs[n][(kc ^ (n & 7)) * 8]) = v;
      }
    }
    __syncthreads();
#pragma unroll
    for (int ks = 0; ks < 2; ++ks) {
      int m = w * 16 + l16;
      int ga = (ks * 4 + quad) ^ (m & 7);
      short8 a = *(const short8*)(&As[m][ga * 8]);
#pragma unroll
      for (int t = 0; t < NT; ++t) {
        int n = t * 16 + l16;
        int gb = (ks * 4 + quad) ^ (n & 7);
        short8 b = *(const short8*)(&Bs[n][gb * 8]);
        acc[t] = __builtin_amdgcn_mfma_f32_16x16x32_bf16(a, b, acc[t], 0, 0, 0);
      }
    }
  }
#pragma unroll
  for (int t = 0; t < NT; ++t) {
    int cc = c0 + t * 16 + l16;
    if (cc >= Ncols) continue;
#pragma unroll
    for (int i = 0; i < 4; ++i) {
      int rr = row0 + w * 16 + quad * 4 + i;
      if (rr >= M) continue;
      float v = acc[t][i];
      if (EPI == 1) {
        unsigned short us = ((const unsigned short*)aux)[(size_t)rr * ldc + cc];
        v = fmaxf(v, bflo((unsigned)us));
      }
      if (EPI == 2) {
        // h1 -> xh interleaved: col cc -> 4*(cc>>1) + 2 + (cc&1)
        ((unsigned short*)Cv)[(size_t)rr * 256 + 4 * (cc >> 1) + 2 + (cc & 1)] = f2bf(v);
      } else if (OUT_BF16)
        ((unsigned short*)Cv)[(size_t)rr * ldc + cc] = f2bf(v);
      else
        ((float*)Cv)[(size_t)rr * ldc + cc] = v;
    }
  }
}

// =============================== Phase C: layer-0 aggregation ===============================
// wave per dst. feat0i row interleaved: bf16 cols 4q,4q+1 = GAT dims 2q,2q+1;
// 4q+2,4q+3 = GCN dims. lane q covers dims 2q,2q+1 (head=q>>3).
// packed f32x2 accumulation (v_pk_fma_f32).
__global__ __launch_bounds__(256) void k_agg0(const unsigned short* __restrict__ feat0i,
                                              const float* __restrict__ logit0,
                                              const int* __restrict__ rowptr,
                                              const uint2* __restrict__ edata,
                                              unsigned short* __restrict__ x1c,
                                              unsigned short* __restrict__ x2,
                                              unsigned short* __restrict__ xh, int N) {
  __shared__ uint2 swl[4][64];
  int wave = threadIdx.x >> 6, lane = threadIdx.x & 63;
  int d = blockIdx.x * 4 + wave;
  if (d >= N) return;
  int head = lane >> 3, hh = lane & 7, j8 = lane >> 3;
  float edv = logit0[(size_t)d * 16 + 8 + hh];
  int beg = rowptr[d], end = rowptr[d + 1], deg = end - beg;
  float l = 0.f, wsum = 0.f;
  f32x2 a2 = {0.f, 0.f}, g2 = {0.f, 0.f};
  for (int base = 0; base < deg; base += 64) {
    int idx = beg + base + lane;
    uint2 sv = make_uint2(0u, 0u);
    if (idx < end) sv = edata[idx];
    swl[wave][lane] = sv;
    int ng = deg - base; if (ng > 64) ng = 64;
    int groups = (ng + 7) >> 3;
    for (int g = 0; g < groups; ++g) {
      uint2 swj = swl[wave][g * 8 + j8];
      float es = logit0[(size_t)swj.x * 16 + hh];
      float lg = es + edv;
      lg = lg > 0.f ? lg : LRELU_ALPHA * lg;
      float pme = __expf(fminf(lg, 80.f));
      if (g * 8 + j8 >= ng) pme = 0.f;
#pragma unroll
      for (int j = 0; j < 8; ++j) {
        uint2 sw = swl[wave][g * 8 + j];
        float pj = __shfl(pme, j * 8 + head, 64);
        float wj = __uint_as_float(sw.y);
        uint2 u = *(const uint2*)(feat0i + (size_t)sw.x * 256 + 4 * lane);
        a2 += bfpair(u.x) * pj;
        g2 += bfpair(u.y) * wj;
        l += pj;
        wsum += wj;
      }
    }
  }
  float inv = l > 0.f ? 1.f / l : 0.f;
  float v0 = a2.x * inv, v1 = a2.y * inv;
  v0 = v0 > 0.f ? v0 : __expf(v0) - 1.f;  // ELU
  v1 = v1 > 0.f ? v1 : __expf(v1) - 1.f;
  unsigned xpack = (unsigned)f2bf(v0) | ((unsigned)f2bf(v1) << 16);
  ((unsigned*)x1c)[(size_t)d * 64 + lane] = xpack;
  ((unsigned*)xh)[(size_t)d * 128 + 2 * lane] = xpack;  // x-pair slot of interleaved row
  float ginv = 1.f / fmaxf(wsum, 1e-16f);
  float w0 = fmaxf(g2.x * ginv, 0.f), w1 = fmaxf(g2.y * ginv, 0.f);
  ((unsigned*)x2)[(size_t)d * 64 + lane] = (unsigned)f2bf(w0) | ((unsigned)f2bf(w1) << 16);
}

// =============================== Phase E: layer-1 aggregation (dst-chunked) ==============
// xh row interleaved: 4q,4q+1 = x1 dims 2q,2q+1; 4q+2,4q+3 = h1 dims.
// distributed p + LDS broadcast; packed f32x2 accumulation.
__global__ __launch_bounds__(256) void k_agg1(const unsigned short* __restrict__ xh,
                                              const float* __restrict__ esed,
                                              const int* __restrict__ rowptr,
                                              const uint2* __restrict__ edata,
                                              unsigned short* __restrict__ aggbuf,
                                              unsigned short* __restrict__ x2f,
                                              int d0, int d1) {
  __shared__ uint2 swl[4][64];
  __shared__ float pl[4][64];
  int wave = threadIdx.x >> 6, lane = threadIdx.x & 63;
  int d = d0 + blockIdx.x * 4 + wave;
  if (d >= d1) return;
  int hh = lane & 7, j8 = lane >> 3;
  float ed = esed[(size_t)d * 16 + 8 + hh];
  int beg = rowptr[d], end = rowptr[d + 1], deg = end - beg;
  f32x2 ax2[8] = {};
  f32x2 g2 = {0.f, 0.f};
  float lpart = 0.f, wsum = 0.f;
  for (int base = 0; base < deg; base += 64) {
    int idx = beg + base + lane;
    uint2 sv = make_uint2(0u, 0u);
    if (idx < end) sv = edata[idx];
    swl[wave][lane] = sv;
    int ng = deg - base; if (ng > 64) ng = 64;
    int groups = (ng + 7) >> 3;
    for (int g = 0; g < groups; ++g) {
      uint2 swj = swl[wave][g * 8 + j8];
      float es = esed[(size_t)swj.x * 16 + hh];
      float lg = es + ed;
      lg = lg > 0.f ? lg : LRELU_ALPHA * lg;
      float pme = __expf(fminf(lg, 80.f));
      if (g * 8 + j8 >= ng) pme = 0.f;
      lpart += pme;
      pl[wave][lane] = pme;
#pragma unroll
      for (int j = 0; j < 8; ++j) {
        uint2 sw = swl[wave][g * 8 + j];
        float4 pv0 = *(const float4*)&pl[wave][j * 8];
        float4 pv1 = *(const float4*)&pl[wave][j * 8 + 4];
        uint2 u = *(const uint2*)(xh + (size_t)sw.x * 256 + 4 * lane);
        f32x2 xv = bfpair(u.x);
        float wj = __uint_as_float(sw.y);
        g2 += bfpair(u.y) * wj;
        wsum += wj;
        ax2[0] += xv * pv0.x;
        ax2[1] += xv * pv0.y;
        ax2[2] += xv * pv0.z;
        ax2[3] += xv * pv0.w;
        ax2[4] += xv * pv1.x;
        ax2[5] += xv * pv1.y;
        ax2[6] += xv * pv1.z;
        ax2[7] += xv * pv1.w;
      }
    }
  }
  // head-sum reduce: lanes congruent mod 8 hold partials of head (lane&7)
  lpart += __shfl_xor(lpart, 8, 64);
  lpart += __shfl_xor(lpart, 16, 64);
  lpart += __shfl_xor(lpart, 32, 64);
  size_t lr = (size_t)(d - d0) * 512;
#pragma unroll
  for (int h = 0; h < 8; ++h) {
    float lh = __shfl(lpart, h, 64);
    float inv = lh > 0.f ? 1.f / lh : 0.f;
    ((unsigned*)aggbuf)[lr + h * 64 + lane] =
        (unsigned)f2bf(ax2[h].x * inv) | ((unsigned)f2bf(ax2[h].y * inv) << 16);
  }
  float ginv = 1.f / fmaxf(wsum, 1e-16f);
  float w0 = fmaxf(g2.x * ginv, 0.f), w1 = fmaxf(g2.y * ginv, 0.f);
  ((unsigned*)x2f)[(size_t)d * 64 + lane] = (unsigned)f2bf(w0) | ((unsigned)f2bf(w1) << 16);
}

// =============================== host launch ===============================

extern "C" void kernel_launch(void* const* d_in, const int* in_sizes, int n_in,
                              void* d_out, int out_size, void* d_ws, size_t ws_size,
                              hipStream_t stream) {
  const float* x   = (const float*)d_in[0];
  const int*   ei  = (const int*)d_in[1];
  const float* ew  = (const float*)d_in[2];
  const float* W0  = (const float*)d_in[3];
  const float* a0s = (const float*)d_in[4];
  const float* a0d = (const float*)d_in[5];
  const float* W1  = (const float*)d_in[6];
  const float* a1s = (const float*)d_in[7];
  const float* a1d = (const float*)d_in[8];
  const float* gw0 = (const float*)d_in[9];
  const float* gw1 = (const float*)d_in[10];
  float* out = (float*)d_out;

  const int N = in_sizes[0] / 128;
  const int E = in_sizes[1] / 2;
  const int* src = ei;
  const int* dst = ei + E;

  // workspace carve (256B aligned); peak ~131 MB (< proven-safe 166 MB)
  char* p = (char*)d_ws;
  auto carve = [&](size_t bytes) {
    void* r = (void*)p;
    p += (bytes + 255) & ~(size_t)255;
    return r;
  };
  int*   cnt    = (int*)carve((size_t)N * 4);
  int*   rowptr = (int*)carve((size_t)(N + 1) * 4);
  int*   cur    = (int*)carve((size_t)N * 4);
  int*   bsum   = (int*)carve(256 * 4);
  uint2* edata  = (uint2*)carve((size_t)E * 8);
  unsigned short* W0catT  = (unsigned short*)carve(32768 * 2);
  float*          logitW  = (float*)carve(2048 * 4);
  unsigned short* gw1T    = (unsigned short*)carve(16384 * 2);
  unsigned short* va1T    = (unsigned short*)carve(2048 * 2);
  unsigned short* WstackT = (unsigned short*)carve(131072 * 2);
  unsigned short* x1c  = (unsigned short*)carve((size_t)N * 128 * 2);
  unsigned short* x2   = (unsigned short*)carve((size_t)N * 128 * 2);
  unsigned short* x2f  = (unsigned short*)carve((size_t)N * 128 * 2);  // bf16 now
  float*          esed = (float*)carve((size_t)N * 16 * 4);
  unsigned short* xh   = (unsigned short*)carve((size_t)N * 256 * 2);
  // scratch union: {xb, feat0i, logit0} then reused as aggbuf
  const int CH = 25600;
  size_t ph1 = ((size_t)N * 128 * 2 + 255) & ~(size_t)255;          // xb
  size_t ph2 = ph1 + (((size_t)N * 256 * 2 + 255) & ~(size_t)255);  // +feat0i
  size_t ph3 = ph2 + (((size_t)N * 16 * 4 + 255) & ~(size_t)255);   // +logit0
  size_t scratch_sz = (size_t)CH * 1024 * 2;
  if (ph3 > scratch_sz) scratch_sz = ph3;
  char* scratch = (char*)carve(scratch_sz);
  unsigned short* xb     = (unsigned short*)scratch;
  unsigned short* feat0i = (unsigned short*)(scratch + ph1);
  float*          logit0 = (float*)(scratch + ph2);
  unsigned short* aggbuf = (unsigned short*)scratch;  // alias, live after agg0

  // Phase A: CSR build (single int atomic; no float atomics anywhere)
  hipMemsetAsync(cnt, 0, (size_t)N * 4, stream);
  int gE = (E + 255) / 256;
  k_count<<<gE, 256, 0, stream>>>(dst, cnt, E);
  int nb = (N + 1023) / 1024;
  k_scan1<<<nb, 1024, 0, stream>>>(cnt, rowptr, bsum, N);
  k_scan2<<<1, 64, 0, stream>>>(bsum, rowptr + N, nb);
  k_scan3<<<nb, 1024, 0, stream>>>(rowptr, cur, bsum, N);
  k_scatter<<<gE, 256, 0, stream>>>(src, dst, ew, cur, edata, E);

  // weight packing + fused x-cast/logit0
  k_pack<<<(184320 + 255) / 256, 256, 0, stream>>>(W0, a0s, a0d, W1, a1s, a1d, gw0,
                                                   gw1, W0catT, logitW, gw1T, va1T,
                                                   WstackT);
  k_prep<<<(N + 15) / 16, 256, 0, stream>>>(x, logitW, xb, logit0, N);

  int gM = (N + 63) / 64;
  // Phase B: feat0i[N,256] bf16 (interleaved cols via W0catT row permutation)
  k_mgemm<8, 1, 0><<<dim3(gM, 2), 256, 0, stream>>>(xb, 128, W0catT, 128, feat0i, 256,
                                                    nullptr, N, 256, 128);
  // Phase C: layer-0 GAT softmax-agg + ELU -> x1c & xh ; GCN agg + ReLU -> x2
  k_agg0<<<(N + 3) / 4, 256, 0, stream>>>(feat0i, logit0, rowptr, edata,
                                          x1c, x2, xh, N);

  // Phase D: esed[N,16] fp32 = x1c @ va1T^T ; h1 = x2 @ gw1T^T -> xh interleaved
  k_mgemm<1, 0, 0><<<dim3(gM, 1), 256, 0, stream>>>(x1c, 128, va1T, 128, esed, 16,
                                                    nullptr, N, 16, 128);
  k_mgemm<8, 1, 2><<<dim3(gM, 1), 256, 0, stream>>>(x2, 128, gw1T, 128, xh, 256,
                                                    nullptr, N, 128, 128);

  // Phase E/F: dst-chunked layer-1 aggregation + MFMA output GEMM (max-fused, bf16 aux)
  for (int d0 = 0; d0 < N; d0 += CH) {
    int d1 = d0 + CH < N ? d0 + CH : N;
    int chN = d1 - d0;
    k_agg1<<<(chN + 3) / 4, 256, 0, stream>>>(xh, esed, rowptr, edata,
                                              aggbuf, x2f, d0, d1);
    k_mgemm<8, 0, 1><<<dim3((chN + 63) / 64, 1), 256, 0, stream>>>(
        aggbuf, 1024, WstackT, 1024, out + (size_t)d0 * 128, 128,
        x2f + (size_t)d0 * 128, chN, 128, 1024);
  }
}